// Round 3
// baseline (383.633 us; speedup 1.0000x reference)
//
#include <hip/hip_runtime.h>
#include <math.h>

// ---------------------------------------------------------------------------
// Problem constants
// ---------------------------------------------------------------------------
#define NROWS 65536          // B*NAG = 8192*8
#define NB    8192           // B
// workspace layout (float offsets)
#define WS_A1   0            // 65536*64  pre-BN actor activations
#define WS_U    4194304      // 65536*64  h @ po1_w[:64]   (j-indexed half)
#define WS_V    8388608      // 65536*64  h @ po1_w[64:]   (i-indexed half)
#define WS_MU   12582912     // 65536*24
#define WS_SIG  14155776     // 65536*24
#define STAT_OFF  15728640   // 448 floats: asum asq usum usq vsum vsq cross
#define DERIV_OFF 15729088   // 256 + 384: ascale ashift pscale pshift | po2^T
// d_out layout (float offsets): x_out, h, KL
#define OUT_XOUT 0
#define OUT_H    917504
#define OUT_KL   5111808

__device__ __forceinline__ float sigmf(float x) { return 1.0f / (1.0f + __expf(-x)); }
__device__ __forceinline__ float tanhfast(float x) {
    x = fminf(fmaxf(x, -15.f), 15.f);
    float e = __expf(-2.f * x);
    return (1.f - e) / (1.f + e);
}

// ---------------------------------------------------------------------------
// K0: zero the global stat accumulators (ws is poisoned 0xAA before each call)
// ---------------------------------------------------------------------------
__global__ void k_init(float* __restrict__ ws) {
    int t = threadIdx.x;
    for (int i = t; i < 448; i += 256) ws[STAT_OFF + i] = 0.f;
}

// ---------------------------------------------------------------------------
// K1: fc1 -> GRU -> {a1, U, V} + BN stat partials.  64 rows/block, 256 thr.
// LDS 44.8 KB -> 3 blocks/CU.  inp staged into a union buffer that becomes
// the x/h buffer after P1 (all reads complete before overwrite).  Weight
// k-loops are chunked (16k in P2, 32k in P3) with per-chunk barriers so the
// block's waves share a <=24 KB L1-resident weight window, and next-k weights
// are register-prefetched one iteration ahead.
// ---------------------------------------------------------------------------
__global__ __launch_bounds__(256) void k_front(
    const float* __restrict__ inp, const float* __restrict__ hin,
    const float* __restrict__ fc1_w, const float* __restrict__ fc1_b,
    const float* __restrict__ w_ih, const float* __restrict__ w_hh,
    const float* __restrict__ b_ih, const float* __restrict__ b_hh,
    const float* __restrict__ aw1_w, const float* __restrict__ aw1_b,
    const float* __restrict__ po1_w,
    float* __restrict__ h_out, float* __restrict__ ws)
{
    __shared__ float s_u[6400];        // inp (64 x stride100); then x/h (64 x stride68)
    __shared__ float s_hin[64 * 68];
    __shared__ float s_stat[448];      // asum asq usum usq vsum vsq cross

    const int t = threadIdx.x;
    const int row0 = blockIdx.x * 64;

    for (int i = t; i < 448; i += 256) s_stat[i] = 0.f;

    // stage inp (64x96 -> stride 100) and h_in (64x64 -> stride 68)
    {
        const float* gi = inp + (size_t)row0 * 96;
        for (int i = t; i < 1536; i += 256) {
            int r = i / 24, q = (i - r * 24) * 4;
            *(float4*)&s_u[r * 100 + q] = *(const float4*)&gi[r * 96 + q];
        }
        const float* gh = hin + (size_t)row0 * 64;
        for (int i = t; i < 1024; i += 256) {
            int r = i >> 4, kc = (i & 15) * 4;
            *(float4*)&s_hin[r * 68 + kc] = *(const float4*)&gh[r * 64 + kc];
        }
    }
    __syncthreads();

    const int c0 = (t & 15) * 4;
    const int r0 = (t >> 4) * 4;

    // ---- P1: x = relu(inp @ fc1_w + fc1_b) ----  (fc1_w = 24 KB, L1-resident)
    float xacc[4][4];
    {
        float bb[4]; *(float4*)bb = *(const float4*)&fc1_b[c0];
        #pragma unroll
        for (int i = 0; i < 4; i++)
            #pragma unroll
            for (int j = 0; j < 4; j++) xacc[i][j] = bb[j];
        float wc[4], wn[4];
        *(float4*)wc = *(const float4*)&fc1_w[c0];
        #pragma unroll 4
        for (int k = 0; k < 96; k++) {
            if (k < 95) *(float4*)wn = *(const float4*)&fc1_w[(k + 1) * 64 + c0];
            #pragma unroll
            for (int i = 0; i < 4; i++) {
                float xv = s_u[(r0 + i) * 100 + k];
                #pragma unroll
                for (int j = 0; j < 4; j++) xacc[i][j] += xv * wc[j];
            }
            if (k < 95) { *(float4*)wc = *(float4*)wn; }
        }
    }
    __syncthreads();   // all P1 reads of s_u(inp) complete
    #pragma unroll
    for (int i = 0; i < 4; i++) {
        float o[4];
        #pragma unroll
        for (int j = 0; j < 4; j++) o[j] = fmaxf(xacc[i][j], 0.f);
        *(float4*)&s_u[(r0 + i) * 68 + c0] = *(float4*)o;
    }
    __syncthreads();

    // ---- P2: GRU gates + nonlinearity ----
    float ho[4][4];
    {
        float ar[4][4], az[4][4], an[4][4], hn[4][4];
        {
            float t0[4], t1[4];
            *(float4*)t0 = *(const float4*)&b_ih[c0];
            *(float4*)t1 = *(const float4*)&b_hh[c0];
            #pragma unroll
            for (int i = 0; i < 4; i++)
                #pragma unroll
                for (int j = 0; j < 4; j++) ar[i][j] = t0[j] + t1[j];
            *(float4*)t0 = *(const float4*)&b_ih[64 + c0];
            *(float4*)t1 = *(const float4*)&b_hh[64 + c0];
            #pragma unroll
            for (int i = 0; i < 4; i++)
                #pragma unroll
                for (int j = 0; j < 4; j++) az[i][j] = t0[j] + t1[j];
            *(float4*)t0 = *(const float4*)&b_ih[128 + c0];
            *(float4*)t1 = *(const float4*)&b_hh[128 + c0];
            #pragma unroll
            for (int i = 0; i < 4; i++)
                #pragma unroll
                for (int j = 0; j < 4; j++) { an[i][j] = t0[j]; hn[i][j] = t1[j]; }
        }

        const float* wbi = w_ih + c0;
        const float* wbh = w_hh + c0;
        for (int kc = 0; kc < 64; kc += 16) {
            float wc[6][4], wn[6][4];
            {
                const float* wi = wbi + kc * 192;
                const float* wh = wbh + kc * 192;
                *(float4*)wc[0] = *(const float4*)&wi[0];
                *(float4*)wc[1] = *(const float4*)&wi[64];
                *(float4*)wc[2] = *(const float4*)&wi[128];
                *(float4*)wc[3] = *(const float4*)&wh[0];
                *(float4*)wc[4] = *(const float4*)&wh[64];
                *(float4*)wc[5] = *(const float4*)&wh[128];
            }
            #pragma unroll 2
            for (int kk = 0; kk < 16; kk++) {
                const int k = kc + kk;
                if (kk < 15) {
                    const float* wi = wbi + (k + 1) * 192;
                    const float* wh = wbh + (k + 1) * 192;
                    *(float4*)wn[0] = *(const float4*)&wi[0];
                    *(float4*)wn[1] = *(const float4*)&wi[64];
                    *(float4*)wn[2] = *(const float4*)&wi[128];
                    *(float4*)wn[3] = *(const float4*)&wh[0];
                    *(float4*)wn[4] = *(const float4*)&wh[64];
                    *(float4*)wn[5] = *(const float4*)&wh[128];
                }
                #pragma unroll
                for (int i = 0; i < 4; i++) {
                    float xv = s_u[(r0 + i) * 68 + k];
                    float hv = s_hin[(r0 + i) * 68 + k];
                    #pragma unroll
                    for (int j = 0; j < 4; j++) {
                        ar[i][j] += xv * wc[0][j] + hv * wc[3][j];
                        az[i][j] += xv * wc[1][j] + hv * wc[4][j];
                        an[i][j] += xv * wc[2][j];
                        hn[i][j] += hv * wc[5][j];
                    }
                }
                if (kk < 15) {
                    #pragma unroll
                    for (int q = 0; q < 6; q++) *(float4*)wc[q] = *(float4*)wn[q];
                }
            }
            __syncthreads();   // keep block's waves in the same 24 KB L1 window
        }
        #pragma unroll
        for (int i = 0; i < 4; i++) {
            #pragma unroll
            for (int j = 0; j < 4; j++) {
                float r = sigmf(ar[i][j]);
                float z = sigmf(az[i][j]);
                float nt = tanhfast(an[i][j] + r * hn[i][j]);
                float hp = s_hin[(r0 + i) * 68 + c0 + j];
                ho[i][j] = (1.f - z) * nt + z * hp;
            }
        }
    }
    // last P2 chunk barrier already ensured all s_u(x) reads done
    #pragma unroll
    for (int i = 0; i < 4; i++) {
        *(float4*)&s_u[(r0 + i) * 68 + c0] = *(float4*)ho[i];
        *(float4*)&h_out[(size_t)(row0 + r0 + i) * 64 + c0] = *(float4*)ho[i];
    }
    __syncthreads();

    // ---- P3: a1 = h@aw1_w + b,  U = h@po1_w[:64],  V = h@po1_w[64:]  + stats ----
    {
        float a_[4][4], u_[4][4], v_[4][4];
        float ab[4]; *(float4*)ab = *(const float4*)&aw1_b[c0];
        #pragma unroll
        for (int i = 0; i < 4; i++)
            #pragma unroll
            for (int j = 0; j < 4; j++) { a_[i][j] = ab[j]; u_[i][j] = 0.f; v_[i][j] = 0.f; }

        for (int kc = 0; kc < 64; kc += 32) {
            float wc[3][4], wn[3][4];
            *(float4*)wc[0] = *(const float4*)&aw1_w[kc * 64 + c0];
            *(float4*)wc[1] = *(const float4*)&po1_w[kc * 64 + c0];
            *(float4*)wc[2] = *(const float4*)&po1_w[(64 + kc) * 64 + c0];
            #pragma unroll 2
            for (int kk = 0; kk < 32; kk++) {
                const int k = kc + kk;
                if (kk < 31) {
                    *(float4*)wn[0] = *(const float4*)&aw1_w[(k + 1) * 64 + c0];
                    *(float4*)wn[1] = *(const float4*)&po1_w[(k + 1) * 64 + c0];
                    *(float4*)wn[2] = *(const float4*)&po1_w[(65 + k) * 64 + c0];
                }
                #pragma unroll
                for (int i = 0; i < 4; i++) {
                    float hv = s_u[(r0 + i) * 68 + k];
                    #pragma unroll
                    for (int j = 0; j < 4; j++) {
                        a_[i][j] += hv * wc[0][j];
                        u_[i][j] += hv * wc[1][j];
                        v_[i][j] += hv * wc[2][j];
                    }
                }
                if (kk < 31) {
                    #pragma unroll
                    for (int q = 0; q < 3; q++) *(float4*)wc[q] = *(float4*)wn[q];
                }
            }
            __syncthreads();
        }

        float* wsa = ws + WS_A1;
        float* wsu = ws + WS_U;
        float* wsv = ws + WS_V;
        #pragma unroll
        for (int i = 0; i < 4; i++) {
            *(float4*)&wsa[(size_t)(row0 + r0 + i) * 64 + c0] = *(float4*)a_[i];
            *(float4*)&wsu[(size_t)(row0 + r0 + i) * 64 + c0] = *(float4*)u_[i];
            *(float4*)&wsv[(size_t)(row0 + r0 + i) * 64 + c0] = *(float4*)v_[i];
        }
        #pragma unroll
        for (int j = 0; j < 4; j++) {
            float sa = 0, sq = 0, su = 0, suq = 0, sv = 0, svq = 0;
            #pragma unroll
            for (int i = 0; i < 4; i++) {
                float x = a_[i][j]; sa += x; sq += x * x;
                float u = u_[i][j]; su += u; suq += u * u;
                float v = v_[i][j]; sv += v; svq += v * v;
            }
            atomicAdd(&s_stat[c0 + j], sa);
            atomicAdd(&s_stat[64 + c0 + j], sq);
            atomicAdd(&s_stat[128 + c0 + j], su);
            atomicAdd(&s_stat[192 + c0 + j], suq);
            atomicAdd(&s_stat[256 + c0 + j], sv);
            atomicAdd(&s_stat[320 + c0 + j], svq);
            // cross-covariance: lanes t and t^16 hold the two 4-row halves of
            // one 8-row b-group (r0 = 4*(t>>4), g = r0/8)
            float ub = su + __shfl_xor(su, 16, 64);
            float vb = sv + __shfl_xor(sv, 16, 64);
            if ((t & 16) == 0)
                atomicAdd(&s_stat[384 + c0 + j], (ub * 0.125f) * (vb * 0.125f));
        }
    }
    __syncthreads();
    if (t < 64) {
        float* gs = ws + STAT_OFF;
        #pragma unroll
        for (int q = 0; q < 7; q++)
            atomicAdd(&gs[q * 64 + t], s_stat[q * 64 + t]);
    }
}

// ---------------------------------------------------------------------------
// K2: finalize BN scale/shift.  Var(U+V) = Var_u + Var_v + 2*(cross/B - Eu*Ev)
// Also transposes po2_w (64x6 -> 6x64) for uniform s_loads in K4.
// ---------------------------------------------------------------------------
__global__ void k_stats(const float* __restrict__ aw_g, const float* __restrict__ aw_be,
                        const float* __restrict__ po_g, const float* __restrict__ po_be,
                        const float* __restrict__ po1_b, const float* __restrict__ po2_w,
                        float* __restrict__ ws)
{
    const int t = threadIdx.x;
    const float* st = ws + STAT_OFF;
    float* dv = ws + DERIV_OFF;
    if (t < 64) {
        const float invN = 1.f / 65536.f;
        float am = st[t] * invN;
        float av = st[64 + t] * invN - am * am;
        float asc = aw_g[t] * rsqrtf(av + 1e-5f);
        dv[t] = asc;
        dv[64 + t] = aw_be[t] - asc * am;
        float Eu = st[128 + t] * invN;
        float vu = st[192 + t] * invN - Eu * Eu;
        float Ev = st[256 + t] * invN;
        float vv = st[320 + t] * invN - Ev * Ev;
        float cov = st[384 + t] * (1.f / 8192.f) - Eu * Ev;
        float my = Eu + Ev + po1_b[t];
        float vy = vu + vv + 2.f * cov;
        float psc = po_g[t] * rsqrtf(vy + 1e-5f);
        dv[128 + t] = psc;
        dv[192 + t] = po_be[t] + psc * (po1_b[t] - my);
    }
    for (int i = t; i < 384; i += 128) {
        int d = i >> 6, c = i & 63;
        dv[256 + i] = po2_w[c * 6 + d];     // po2^T [6][64]
    }
}

// ---------------------------------------------------------------------------
// K3: actor head.  32 rows/block, 256 thr, LDS 24 KB -> 6 blocks/CU.
// ---------------------------------------------------------------------------
__global__ __launch_bounds__(256) void k_aw(
    float* __restrict__ ws, const float* __restrict__ h_glob,
    const float* __restrict__ noise,
    const float* __restrict__ aw2_w, const float* __restrict__ aw2_b,
    const float* __restrict__ fc2_w, const float* __restrict__ fc2_b,
    float* __restrict__ out)
{
    __shared__ float s_a[32 * 68];    // overlaid by s_c after the GEMM
    __shared__ float s_h[32 * 68];
    __shared__ float s_aw[32 * 52];
    const int t = threadIdx.x;
    const int row0 = blockIdx.x * 32;
    const float* a1 = ws + WS_A1;
    const float* dv = ws + DERIV_OFF;

    for (int i = t; i < 512; i += 256) {
        int r = i >> 4, kc = (i & 15) * 4;
        float a_[4]; *(float4*)a_ = *(const float4*)&a1[(size_t)(row0 + r) * 64 + kc];
        float sc[4]; *(float4*)sc = *(const float4*)&dv[kc];
        float sf[4]; *(float4*)sf = *(const float4*)&dv[64 + kc];
        float o[4];
        #pragma unroll
        for (int j = 0; j < 4; j++) o[j] = fmaxf(sc[j] * a_[j] + sf[j], 0.f);
        *(float4*)&s_a[r * 68 + kc] = *(float4*)o;
        *(float4*)&s_h[r * 68 + kc] = *(const float4*)&h_glob[(size_t)(row0 + r) * 64 + kc];
    }
    __syncthreads();

    const int cg = t & 15, rg = t >> 4;
    const int c0 = cg * 4, r0 = rg * 2;
    if (cg < 12) {                      // 48 output cols
        float acc[2][4];
        float bb[4]; *(float4*)bb = *(const float4*)&aw2_b[c0];
        #pragma unroll
        for (int i = 0; i < 2; i++)
            #pragma unroll
            for (int j = 0; j < 4; j++) acc[i][j] = bb[j];
        #pragma unroll 4
        for (int k = 0; k < 64; k++) {
            float w[4]; *(float4*)w = *(const float4*)&aw2_w[k * 48 + c0];
            #pragma unroll
            for (int i = 0; i < 2; i++) {
                float av = s_a[(r0 + i) * 68 + k];
                #pragma unroll
                for (int j = 0; j < 4; j++) acc[i][j] += av * w[j];
            }
        }
        #pragma unroll
        for (int i = 0; i < 2; i++)
            *(float4*)&s_aw[(r0 + i) * 52 + c0] = *(float4*)acc[i];
    }
    __syncthreads();

    float* ws_mu = ws + WS_MU;
    float* ws_sig = ws + WS_SIG;
    float* s_c = s_a;                  // overlay (stride 28), s_a dead now
    for (int idx = t; idx < 768; idx += 256) {
        int r = idx / 24, m = idx - r * 24;
        int grow = row0 + r;
        float mu = s_aw[r * 52 + m];
        float sg = fmaxf(__expf(s_aw[r * 52 + 24 + m]), 0.2f);
        ws_mu[(size_t)grow * 24 + m] = mu;
        ws_sig[(size_t)grow * 24 + m] = sg;
        s_c[r * 28 + m] = mu + sqrtf(sg) * noise[(size_t)grow * 24 + m];
    }
    __syncthreads();

    float* xout = out + OUT_XOUT;
    for (int o = t; o < 448; o += 256) {
        int r = o / 14, c = o - r * 14;
        float acc = fc2_b[c];
        #pragma unroll 4
        for (int k = 0; k < 64; k++) acc += s_h[r * 68 + k] * fc2_w[k * 14 + c];
        #pragma unroll 4
        for (int k = 0; k < 24; k++) acc += s_c[r * 28 + k] * fc2_w[(64 + k) * 14 + c];
        xout[(size_t)(row0 + r) * 14 + c] = acc;
    }
}

// ---------------------------------------------------------------------------
// K4: critic head.  8 b per block, 256 threads (4 waves/block), LDS 35 KB
// -> 4 blocks/CU.  Thread owns (b, i, 2 j's).
// ---------------------------------------------------------------------------
__global__ __launch_bounds__(256) void k_po(
    const float* __restrict__ ws, const float* __restrict__ po2_b,
    float* __restrict__ kl_out)
{
    __shared__ float s_U[64 * 68];
    __shared__ float s_V[64 * 68];   // overlaid by s_out (stride 48) after GEMM
    __shared__ float s_kl[64];
    const int t = threadIdx.x;
    const int b0 = blockIdx.x * 8;
    const float* U = ws + WS_U;
    const float* V = ws + WS_V;
    const float* dv = ws + DERIV_OFF;
    const float* psc = dv + 128;
    const float* psh = dv + 192;
    const float* p2t = dv + 256;   // [6][64]

    for (int i = t; i < 1024; i += 256) {
        int r = i >> 4, kc = (i & 15) * 4;
        *(float4*)&s_U[r * 68 + kc] = *(const float4*)&U[(size_t)(b0 * 8 + r) * 64 + kc];
        *(float4*)&s_V[r * 68 + kc] = *(const float4*)&V[(size_t)(b0 * 8 + r) * 64 + kc];
    }
    __syncthreads();

    const int bl = t >> 5;            // local b (0..7)
    const int rem = t & 31;
    const int i_ = rem >> 2;          // i (0..7)
    const int j0 = (rem & 3) * 2;     // j base (0,2,4,6)
    float acc[2][6];
    #pragma unroll
    for (int jj = 0; jj < 2; jj++)
        #pragma unroll
        for (int d = 0; d < 6; d++) acc[jj][d] = 0.f;

    for (int c = 0; c < 64; c += 4) {
        float vv[4]; *(float4*)vv = *(const float4*)&s_V[(bl * 8 + i_) * 68 + c];
        float ps[4]; *(float4*)ps = *(const float4*)&psc[c];   // uniform -> s_load
        float pf[4]; *(float4*)pf = *(const float4*)&psh[c];
        float w[6][4];
        #pragma unroll
        for (int d = 0; d < 6; d++) *(float4*)w[d] = *(const float4*)&p2t[d * 64 + c];
        #pragma unroll
        for (int jj = 0; jj < 2; jj++) {
            float uu[4]; *(float4*)uu = *(const float4*)&s_U[(bl * 8 + j0 + jj) * 68 + c];
            float p[4];
            #pragma unroll
            for (int q = 0; q < 4; q++) p[q] = fmaxf(ps[q] * (uu[q] + vv[q]) + pf[q], 0.f);
            #pragma unroll
            for (int d = 0; d < 6; d++)
                acc[jj][d] += p[0] * w[d][0] + p[1] * w[d][1] + p[2] * w[d][2] + p[3] * w[d][3];
        }
    }
    __syncthreads();                  // all GEMM reads of s_U/s_V complete
    float* s_out = s_V;               // overlay, stride 48
    float b2[6];
    #pragma unroll
    for (int d = 0; d < 6; d++) b2[d] = po2_b[d];
    #pragma unroll
    for (int jj = 0; jj < 2; jj++)
        #pragma unroll
        for (int d = 0; d < 6; d++)
            s_out[(bl * 8 + i_) * 48 + (j0 + jj) * 6 + d] = acc[jj][d] + b2[d];
    __syncthreads();

    if (t < 64) {
        const float* ws_mu = ws + WS_MU;
        const float* ws_sig = ws + WS_SIG;
        int grow = (b0 + (t >> 3)) * 8 + (t & 7);
        float s = 0.f;
        #pragma unroll
        for (int m4 = 0; m4 < 6; m4++) {
            float mu0[4]; *(float4*)mu0 = *(const float4*)&ws_mu[(size_t)grow * 24 + m4 * 4];
            float sg0[4]; *(float4*)sg0 = *(const float4*)&ws_sig[(size_t)grow * 24 + m4 * 4];
            #pragma unroll
            for (int q = 0; q < 4; q++) {
                int m = m4 * 4 + q;
                float mu1 = s_out[t * 48 + m];
                float sg1 = fmaxf(__expf(s_out[t * 48 + 24 + m]), 0.2f);
                float d0 = mu0[q] - mu1;
                s += __logf(sg1 / sg0[q]) + (sg0[q] + d0 * d0) / sg1 - 1.f;
            }
        }
        s_kl[t] = s;
    }
    __syncthreads();
    if (t < 8) {
        float s = 0.f;
        #pragma unroll
        for (int i = 0; i < 8; i++) s += s_kl[t * 8 + i];
        kl_out[b0 + t] = s * (0.5f / 192.f);
    }
}

// ---------------------------------------------------------------------------
extern "C" void kernel_launch(void* const* d_in, const int* in_sizes, int n_in,
                              void* d_out, int out_size, void* d_ws, size_t ws_size,
                              hipStream_t stream)
{
    (void)in_sizes; (void)n_in; (void)out_size; (void)ws_size;
    const float* inp   = (const float*)d_in[0];
    const float* hin   = (const float*)d_in[1];
    const float* noise = (const float*)d_in[2];
    const float* fc1_w = (const float*)d_in[3];
    const float* fc1_b = (const float*)d_in[4];
    const float* w_ih  = (const float*)d_in[5];
    const float* w_hh  = (const float*)d_in[6];
    const float* b_ih  = (const float*)d_in[7];
    const float* b_hh  = (const float*)d_in[8];
    const float* aw1_w = (const float*)d_in[9];
    const float* aw1_b = (const float*)d_in[10];
    const float* aw_g  = (const float*)d_in[11];
    const float* aw_be = (const float*)d_in[12];
    const float* aw2_w = (const float*)d_in[13];
    const float* aw2_b = (const float*)d_in[14];
    const float* po1_w = (const float*)d_in[15];
    const float* po1_b = (const float*)d_in[16];
    const float* po_g  = (const float*)d_in[17];
    const float* po_be = (const float*)d_in[18];
    const float* po2_w = (const float*)d_in[19];
    const float* po2_b = (const float*)d_in[20];
    const float* fc2_w = (const float*)d_in[21];
    const float* fc2_b = (const float*)d_in[22];
    float* out = (float*)d_out;
    float* ws  = (float*)d_ws;

    hipLaunchKernelGGL(k_init,  dim3(1),    dim3(256), 0, stream, ws);
    hipLaunchKernelGGL(k_front, dim3(1024), dim3(256), 0, stream,
                       inp, hin, fc1_w, fc1_b, w_ih, w_hh, b_ih, b_hh,
                       aw1_w, aw1_b, po1_w, out + OUT_H, ws);
    hipLaunchKernelGGL(k_stats, dim3(1),    dim3(128), 0, stream,
                       aw_g, aw_be, po_g, po_be, po1_b, po2_w, ws);
    hipLaunchKernelGGL(k_aw,    dim3(2048), dim3(256), 0, stream,
                       ws, out + OUT_H, noise, aw2_w, aw2_b, fc2_w, fc2_b, out);
    hipLaunchKernelGGL(k_po,    dim3(1024), dim3(256), 0, stream,
                       ws, po2_b, out + OUT_KL);
}

// Round 4
// 287.622 us; speedup vs baseline: 1.3338x; 1.3338x over previous
//
#include <hip/hip_runtime.h>
#include <math.h>

// ---------------------------------------------------------------------------
// Problem constants
// ---------------------------------------------------------------------------
#define NROWS 65536          // B*NAG = 8192*8
#define NB    8192           // B
// workspace layout (float offsets)
#define WS_A1   0            // 65536*64  pre-BN actor activations
#define WS_U    4194304      // 65536*64  h @ po1_w[:64]   (j-indexed half)
#define WS_V    8388608      // 65536*64  h @ po1_w[64:]   (i-indexed half)
#define WS_MU   12582912     // 65536*24
#define WS_SIG  14155776     // 65536*24
#define STAT_OFF  15728640   // 448 floats: asum asq usum usq vsum vsq cross
#define DERIV_OFF 15729088   // 256 + 384: ascale ashift pscale pshift | po2^T
#define WPACK_OFF 15729728   // 43008 ushort (21504 floats): packed bf16 weights
// d_out layout (float offsets): x_out, h, KL
#define OUT_XOUT 0
#define OUT_H    917504
#define OUT_KL   5111808

typedef __attribute__((ext_vector_type(8))) short bhalf8;
typedef __attribute__((ext_vector_type(4))) float floatx4;
typedef __attribute__((ext_vector_type(4))) unsigned short u16x4;

__device__ __forceinline__ float sigmf(float x) { return 1.0f / (1.0f + __expf(-x)); }
__device__ __forceinline__ float tanhfast(float x) {
    x = fminf(fmaxf(x, -15.f), 15.f);
    float e = __expf(-2.f * x);
    return (1.f - e) / (1.f + e);
}
__device__ __forceinline__ unsigned short f2bf(float f) {   // RNE fp32->bf16
    unsigned int u = __float_as_uint(f);
    u += 0x7FFFu + ((u >> 16) & 1u);
    return (unsigned short)(u >> 16);
}

// ---------------------------------------------------------------------------
// K0 (k_prep): zero stat accumulators + pack all k_front weights into bf16
// MFMA B-fragment order.  Fragment f = 16 cols x 32 k block; per lane
// (n=lane&15, quad=lane>>4) 8 contiguous bf16 for k = quad*8+j.
//   wp1: fc1_w  [96][64]  -> 4 ntiles x 3 kchunks  (768 frags)
//   wp2: w_ih/w_hh [64][192] -> 24 ntiles x 2 kchunks (3072 frags)
//        tiles 0-3 ir, 4-7 iz, 8-11 in (w_ih); 12-15 hr, 16-19 hz, 20-23 hn
//   wp3: aw1_w / po1_w[:64] / po1_w[64:] -> 12 ntiles x 2 kchunks (1536 frags)
// ---------------------------------------------------------------------------
__global__ void k_prep(const float* __restrict__ fc1_w,
                       const float* __restrict__ w_ih, const float* __restrict__ w_hh,
                       const float* __restrict__ aw1_w, const float* __restrict__ po1_w,
                       float* __restrict__ ws)
{
    const int t = threadIdx.x;
    if (blockIdx.x == 0)
        for (int i = t; i < 448; i += 256) ws[STAT_OFF + i] = 0.f;

    unsigned short* wpk = (unsigned short*)(ws + WPACK_OFF);
    for (int f = blockIdx.x * 256 + t; f < 5376; f += gridDim.x * 256) {
        int lane, c, tile, dst;
        const float* src;
        int colstride, colbase, krowstride, kofs;
        if (f < 768) {            // wp1
            tile = f / 192; c = (f % 192) / 64; lane = f % 64;
            dst = f * 8;
            src = fc1_w; krowstride = 64; colbase = tile * 16; kofs = 0;
        } else if (f < 3840) {    // wp2
            int f2 = f - 768;
            tile = f2 / 128; c = (f2 % 128) / 64; lane = f2 % 64;
            dst = 6144 + f2 * 8;
            if (tile < 12) { src = w_ih; colbase = tile * 16; }
            else           { src = w_hh; colbase = (tile - 12) * 16; }
            krowstride = 192; kofs = 0;
        } else {                  // wp3
            int f3 = f - 3840;
            tile = f3 / 128; c = (f3 % 128) / 64; lane = f3 % 64;
            dst = 30720 + f3 * 8;
            if (tile < 4)       { src = aw1_w; colbase = tile * 16; kofs = 0; }
            else if (tile < 8)  { src = po1_w; colbase = (tile - 4) * 16; kofs = 0; }
            else                { src = po1_w; colbase = (tile - 8) * 16; kofs = 64; }
            krowstride = 64;
        }
        int n = lane & 15, quad = lane >> 4;
        int col = colbase + n;
        unsigned short o[8];
        #pragma unroll
        for (int j = 0; j < 8; j++) {
            int k = c * 32 + quad * 8 + j + kofs;
            o[j] = f2bf(src[(size_t)k * krowstride + col]);
        }
        u16x4 lo, hi;
        lo.x = o[0]; lo.y = o[1]; lo.z = o[2]; lo.w = o[3];
        hi.x = o[4]; hi.y = o[5]; hi.z = o[6]; hi.w = o[7];
        *(u16x4*)&wpk[dst]     = lo;
        *(u16x4*)&wpk[dst + 4] = hi;
    }
}

// ---------------------------------------------------------------------------
// K1: fc1 -> GRU -> {a1, U, V} + BN stat partials.  64 rows/block, 256 thr
// (4 waves, 16 rows/wave), bf16 MFMA 16x16x32 for all three GEMM phases.
// LDS ~37.6 KB.  Activations bf16 in LDS (strides 104/88: 2-way bank = free);
// weights from the packed global arrays, one coalesced dwordx4 per fragment.
// ---------------------------------------------------------------------------
__global__ __launch_bounds__(256) void k_front(
    const float* __restrict__ inp, const float* __restrict__ hin,
    const float* __restrict__ fc1_b,
    const float* __restrict__ b_ih, const float* __restrict__ b_hh,
    const float* __restrict__ aw1_b,
    float* __restrict__ h_out, float* __restrict__ ws)
{
    __shared__ unsigned short s_inpb[64 * 104];  // inp bf16; later h bf16 (stride 88)
    __shared__ unsigned short s_hinb[64 * 88];   // h_in bf16
    __shared__ unsigned short s_xb[64 * 88];     // x bf16
    __shared__ float s_stat[448];

    const int t = threadIdx.x;
    const int row0 = blockIdx.x * 64;
    const int lane = t & 63;
    const int w = t >> 6;
    const int n16 = lane & 15;
    const int quad = lane >> 4;
    const int mrow = w * 16 + n16;        // A-fragment row

    // ---- stage: inp + h_in -> bf16 LDS ----
    {
        const float* gi = inp + (size_t)row0 * 96;
        for (int i = t; i < 1536; i += 256) {
            int r = i / 24, c4 = (i - r * 24) * 4;
            float4 v = *(const float4*)&gi[r * 96 + c4];
            u16x4 p; p.x = f2bf(v.x); p.y = f2bf(v.y); p.z = f2bf(v.z); p.w = f2bf(v.w);
            *(u16x4*)&s_inpb[r * 104 + c4] = p;
        }
        const float* gh = hin + (size_t)row0 * 64;
        for (int i = t; i < 1024; i += 256) {
            int r = i >> 4, c4 = (i & 15) * 4;
            float4 v = *(const float4*)&gh[r * 64 + c4];
            u16x4 p; p.x = f2bf(v.x); p.y = f2bf(v.y); p.z = f2bf(v.z); p.w = f2bf(v.w);
            *(u16x4*)&s_hinb[r * 88 + c4] = p;
        }
    }
    for (int i = t; i < 448; i += 256) s_stat[i] = 0.f;
    __syncthreads();

    const bhalf8* wp1 = (const bhalf8*)((const unsigned short*)(ws + WPACK_OFF));
    const bhalf8* wp2 = wp1 + 768;
    const bhalf8* wp3 = wp1 + 3840;

    // ---- P1: x = relu(inp @ fc1_w + b) ----
    {
        bhalf8 ai0 = *(const bhalf8*)&s_inpb[mrow * 104 + 0  + quad * 8];
        bhalf8 ai1 = *(const bhalf8*)&s_inpb[mrow * 104 + 32 + quad * 8];
        bhalf8 ai2 = *(const bhalf8*)&s_inpb[mrow * 104 + 64 + quad * 8];
        floatx4 g1[4];
        #pragma unroll
        for (int g = 0; g < 4; g++) {
            floatx4 d = {0.f, 0.f, 0.f, 0.f};
            d = __builtin_amdgcn_mfma_f32_16x16x32_bf16(ai0, wp1[(g * 3 + 0) * 64 + lane], d, 0, 0, 0);
            d = __builtin_amdgcn_mfma_f32_16x16x32_bf16(ai1, wp1[(g * 3 + 1) * 64 + lane], d, 0, 0, 0);
            d = __builtin_amdgcn_mfma_f32_16x16x32_bf16(ai2, wp1[(g * 3 + 2) * 64 + lane], d, 0, 0, 0);
            g1[g] = d;
        }
        #pragma unroll
        for (int g = 0; g < 4; g++) {
            int col = g * 16 + n16;
            float bb = fc1_b[col];
            #pragma unroll
            for (int q = 0; q < 4; q++) {
                float xv = fmaxf(g1[g][q] + bb, 0.f);
                s_xb[(w * 16 + quad * 4 + q) * 88 + col] = f2bf(xv);
            }
        }
    }
    // no barrier needed: each wave reads only its own 16 rows of s_xb

    // ---- P2 MFMA: gi = x@w_ih, gh = h_in@w_hh  (24 n-tiles) ----
    floatx4 g2[24];
    {
        bhalf8 ax0 = *(const bhalf8*)&s_xb[mrow * 88 + 0  + quad * 8];
        bhalf8 ax1 = *(const bhalf8*)&s_xb[mrow * 88 + 32 + quad * 8];
        bhalf8 ah0 = *(const bhalf8*)&s_hinb[mrow * 88 + 0  + quad * 8];
        bhalf8 ah1 = *(const bhalf8*)&s_hinb[mrow * 88 + 32 + quad * 8];
        #pragma unroll
        for (int tt = 0; tt < 12; tt++) {
            floatx4 d = {0.f, 0.f, 0.f, 0.f};
            d = __builtin_amdgcn_mfma_f32_16x16x32_bf16(ax0, wp2[(tt * 2 + 0) * 64 + lane], d, 0, 0, 0);
            d = __builtin_amdgcn_mfma_f32_16x16x32_bf16(ax1, wp2[(tt * 2 + 1) * 64 + lane], d, 0, 0, 0);
            g2[tt] = d;
        }
        #pragma unroll
        for (int tt = 12; tt < 24; tt++) {
            floatx4 d = {0.f, 0.f, 0.f, 0.f};
            d = __builtin_amdgcn_mfma_f32_16x16x32_bf16(ah0, wp2[(tt * 2 + 0) * 64 + lane], d, 0, 0, 0);
            d = __builtin_amdgcn_mfma_f32_16x16x32_bf16(ah1, wp2[(tt * 2 + 1) * 64 + lane], d, 0, 0, 0);
            g2[tt] = d;
        }
    }
    __syncthreads();   // all LDS reads of s_inpb/s_xb done before s_hb overlay

    // ---- P2 post: gates -> h; write h_out + bf16 h into LDS (overlay) ----
    unsigned short* s_hb = s_inpb;   // stride 88
    #pragma unroll
    for (int g = 0; g < 4; g++) {
        int col = g * 16 + n16;
        float br_ = b_ih[col] + b_hh[col];
        float bz_ = b_ih[64 + col] + b_hh[64 + col];
        float bin_ = b_ih[128 + col];
        float bhn_ = b_hh[128 + col];
        #pragma unroll
        for (int q = 0; q < 4; q++) {
            int lrow = w * 16 + quad * 4 + q;
            size_t grow = (size_t)(row0 + lrow);
            float r  = sigmf(g2[g][q] + g2[12 + g][q] + br_);
            float z  = sigmf(g2[4 + g][q] + g2[16 + g][q] + bz_);
            float nt = tanhfast(g2[8 + g][q] + bin_ + r * (g2[20 + g][q] + bhn_));
            float hp = hin[grow * 64 + col];
            float h  = (1.f - z) * nt + z * hp;
            h_out[grow * 64 + col] = h;
            s_hb[lrow * 88 + col] = f2bf(h);
        }
    }
    // own-wave rows only -> no barrier before P3 A-frag reads

    // ---- P3 MFMA: a1/U/V (12 n-tiles) + stats ----
    {
        bhalf8 ah0 = *(const bhalf8*)&s_hb[mrow * 88 + 0  + quad * 8];
        bhalf8 ah1 = *(const bhalf8*)&s_hb[mrow * 88 + 32 + quad * 8];
        floatx4 g3[12];
        #pragma unroll
        for (int tt = 0; tt < 12; tt++) {
            floatx4 d = {0.f, 0.f, 0.f, 0.f};
            d = __builtin_amdgcn_mfma_f32_16x16x32_bf16(ah0, wp3[(tt * 2 + 0) * 64 + lane], d, 0, 0, 0);
            d = __builtin_amdgcn_mfma_f32_16x16x32_bf16(ah1, wp3[(tt * 2 + 1) * 64 + lane], d, 0, 0, 0);
            g3[tt] = d;
        }
        float* wsa = ws + WS_A1;
        float* wsu = ws + WS_U;
        float* wsv = ws + WS_V;
        #pragma unroll
        for (int g = 0; g < 4; g++) {
            int col = g * 16 + n16;
            float ab = aw1_b[col];
            float s1 = 0.f, s2 = 0.f;
            #pragma unroll
            for (int q = 0; q < 4; q++) {
                size_t grow = (size_t)(row0 + w * 16 + quad * 4 + q);
                float v = g3[g][q] + ab;
                wsa[grow * 64 + col] = v;
                s1 += v; s2 += v * v;
            }
            float t1 = s1 + __shfl_xor(s1, 16, 64); t1 += __shfl_xor(t1, 32, 64);
            float t2 = s2 + __shfl_xor(s2, 16, 64); t2 += __shfl_xor(t2, 32, 64);
            if (quad == 0) {
                atomicAdd(&s_stat[col], t1);
                atomicAdd(&s_stat[64 + col], t2);
            }
        }
        #pragma unroll
        for (int g = 0; g < 4; g++) {
            int col = g * 16 + n16;
            float su = 0.f, suq = 0.f, sv = 0.f, svq = 0.f;
            #pragma unroll
            for (int q = 0; q < 4; q++) {
                size_t grow = (size_t)(row0 + w * 16 + quad * 4 + q);
                float uv = g3[4 + g][q]; wsu[grow * 64 + col] = uv; su += uv; suq += uv * uv;
                float vv = g3[8 + g][q]; wsv[grow * 64 + col] = vv; sv += vv; svq += vv * vv;
            }
            float u8 = su + __shfl_xor(su, 16, 64);
            float v8 = sv + __shfl_xor(sv, 16, 64);
            if ((quad & 1) == 0)          // quad 0: even 8-row b-group; quad 2: odd
                atomicAdd(&s_stat[384 + col], u8 * v8 * (1.f / 64.f));
            float su16 = u8 + __shfl_xor(u8, 32, 64);
            float sv16 = v8 + __shfl_xor(v8, 32, 64);
            float suq16 = suq + __shfl_xor(suq, 16, 64); suq16 += __shfl_xor(suq16, 32, 64);
            float svq16 = svq + __shfl_xor(svq, 16, 64); svq16 += __shfl_xor(svq16, 32, 64);
            if (quad == 0) {
                atomicAdd(&s_stat[128 + col], su16);
                atomicAdd(&s_stat[192 + col], suq16);
                atomicAdd(&s_stat[256 + col], sv16);
                atomicAdd(&s_stat[320 + col], svq16);
            }
        }
    }
    __syncthreads();
    if (t < 64) {
        float* gs = ws + STAT_OFF;
        #pragma unroll
        for (int q = 0; q < 7; q++)
            atomicAdd(&gs[q * 64 + t], s_stat[q * 64 + t]);
    }
}

// ---------------------------------------------------------------------------
// K2: finalize BN scale/shift.  Var(U+V) = Var_u + Var_v + 2*(cross/B - Eu*Ev)
// Also transposes po2_w (64x6 -> 6x64) for uniform s_loads in K4.
// ---------------------------------------------------------------------------
__global__ void k_stats(const float* __restrict__ aw_g, const float* __restrict__ aw_be,
                        const float* __restrict__ po_g, const float* __restrict__ po_be,
                        const float* __restrict__ po1_b, const float* __restrict__ po2_w,
                        float* __restrict__ ws)
{
    const int t = threadIdx.x;
    const float* st = ws + STAT_OFF;
    float* dv = ws + DERIV_OFF;
    if (t < 64) {
        const float invN = 1.f / 65536.f;
        float am = st[t] * invN;
        float av = st[64 + t] * invN - am * am;
        float asc = aw_g[t] * rsqrtf(av + 1e-5f);
        dv[t] = asc;
        dv[64 + t] = aw_be[t] - asc * am;
        float Eu = st[128 + t] * invN;
        float vu = st[192 + t] * invN - Eu * Eu;
        float Ev = st[256 + t] * invN;
        float vv = st[320 + t] * invN - Ev * Ev;
        float cov = st[384 + t] * (1.f / 8192.f) - Eu * Ev;
        float my = Eu + Ev + po1_b[t];
        float vy = vu + vv + 2.f * cov;
        float psc = po_g[t] * rsqrtf(vy + 1e-5f);
        dv[128 + t] = psc;
        dv[192 + t] = po_be[t] + psc * (po1_b[t] - my);
    }
    for (int i = t; i < 384; i += 128) {
        int d = i >> 6, c = i & 63;
        dv[256 + i] = po2_w[c * 6 + d];     // po2^T [6][64]
    }
}

// ---------------------------------------------------------------------------
// K3: actor head.  32 rows/block, 256 thr, LDS 24 KB -> 6 blocks/CU.
// ---------------------------------------------------------------------------
__global__ __launch_bounds__(256) void k_aw(
    float* __restrict__ ws, const float* __restrict__ h_glob,
    const float* __restrict__ noise,
    const float* __restrict__ aw2_w, const float* __restrict__ aw2_b,
    const float* __restrict__ fc2_w, const float* __restrict__ fc2_b,
    float* __restrict__ out)
{
    __shared__ float s_a[32 * 68];    // overlaid by s_c after the GEMM
    __shared__ float s_h[32 * 68];
    __shared__ float s_aw[32 * 52];
    const int t = threadIdx.x;
    const int row0 = blockIdx.x * 32;
    const float* a1 = ws + WS_A1;
    const float* dv = ws + DERIV_OFF;

    for (int i = t; i < 512; i += 256) {
        int r = i >> 4, kc = (i & 15) * 4;
        float a_[4]; *(float4*)a_ = *(const float4*)&a1[(size_t)(row0 + r) * 64 + kc];
        float sc[4]; *(float4*)sc = *(const float4*)&dv[kc];
        float sf[4]; *(float4*)sf = *(const float4*)&dv[64 + kc];
        float o[4];
        #pragma unroll
        for (int j = 0; j < 4; j++) o[j] = fmaxf(sc[j] * a_[j] + sf[j], 0.f);
        *(float4*)&s_a[r * 68 + kc] = *(float4*)o;
        *(float4*)&s_h[r * 68 + kc] = *(const float4*)&h_glob[(size_t)(row0 + r) * 64 + kc];
    }
    __syncthreads();

    const int cg = t & 15, rg = t >> 4;
    const int c0 = cg * 4, r0 = rg * 2;
    if (cg < 12) {                      // 48 output cols
        float acc[2][4];
        float bb[4]; *(float4*)bb = *(const float4*)&aw2_b[c0];
        #pragma unroll
        for (int i = 0; i < 2; i++)
            #pragma unroll
            for (int j = 0; j < 4; j++) acc[i][j] = bb[j];
        #pragma unroll 4
        for (int k = 0; k < 64; k++) {
            float w[4]; *(float4*)w = *(const float4*)&aw2_w[k * 48 + c0];
            #pragma unroll
            for (int i = 0; i < 2; i++) {
                float av = s_a[(r0 + i) * 68 + k];
                #pragma unroll
                for (int j = 0; j < 4; j++) acc[i][j] += av * w[j];
            }
        }
        #pragma unroll
        for (int i = 0; i < 2; i++)
            *(float4*)&s_aw[(r0 + i) * 52 + c0] = *(float4*)acc[i];
    }
    __syncthreads();

    float* ws_mu = ws + WS_MU;
    float* ws_sig = ws + WS_SIG;
    float* s_c = s_a;                  // overlay (stride 28), s_a dead now
    for (int idx = t; idx < 768; idx += 256) {
        int r = idx / 24, m = idx - r * 24;
        int grow = row0 + r;
        float mu = s_aw[r * 52 + m];
        float sg = fmaxf(__expf(s_aw[r * 52 + 24 + m]), 0.2f);
        ws_mu[(size_t)grow * 24 + m] = mu;
        ws_sig[(size_t)grow * 24 + m] = sg;
        s_c[r * 28 + m] = mu + sqrtf(sg) * noise[(size_t)grow * 24 + m];
    }
    __syncthreads();

    float* xout = out + OUT_XOUT;
    for (int o = t; o < 448; o += 256) {
        int r = o / 14, c = o - r * 14;
        float acc = fc2_b[c];
        #pragma unroll 4
        for (int k = 0; k < 64; k++) acc += s_h[r * 68 + k] * fc2_w[k * 14 + c];
        #pragma unroll 4
        for (int k = 0; k < 24; k++) acc += s_c[r * 28 + k] * fc2_w[(64 + k) * 14 + c];
        xout[(size_t)(row0 + r) * 14 + c] = acc;
    }
}

// ---------------------------------------------------------------------------
// K4: critic head.  8 b per block, 256 threads (4 waves/block), LDS 35 KB
// -> 4 blocks/CU.  Thread owns (b, i, 2 j's).
// ---------------------------------------------------------------------------
__global__ __launch_bounds__(256) void k_po(
    const float* __restrict__ ws, const float* __restrict__ po2_b,
    float* __restrict__ kl_out)
{
    __shared__ float s_U[64 * 68];
    __shared__ float s_V[64 * 68];   // overlaid by s_out (stride 48) after GEMM
    __shared__ float s_kl[64];
    const int t = threadIdx.x;
    const int b0 = blockIdx.x * 8;
    const float* U = ws + WS_U;
    const float* V = ws + WS_V;
    const float* dv = ws + DERIV_OFF;
    const float* psc = dv + 128;
    const float* psh = dv + 192;
    const float* p2t = dv + 256;   // [6][64]

    for (int i = t; i < 1024; i += 256) {
        int r = i >> 4, kc = (i & 15) * 4;
        *(float4*)&s_U[r * 68 + kc] = *(const float4*)&U[(size_t)(b0 * 8 + r) * 64 + kc];
        *(float4*)&s_V[r * 68 + kc] = *(const float4*)&V[(size_t)(b0 * 8 + r) * 64 + kc];
    }
    __syncthreads();

    const int bl = t >> 5;            // local b (0..7)
    const int rem = t & 31;
    const int i_ = rem >> 2;          // i (0..7)
    const int j0 = (rem & 3) * 2;     // j base (0,2,4,6)
    float acc[2][6];
    #pragma unroll
    for (int jj = 0; jj < 2; jj++)
        #pragma unroll
        for (int d = 0; d < 6; d++) acc[jj][d] = 0.f;

    for (int c = 0; c < 64; c += 4) {
        float vv[4]; *(float4*)vv = *(const float4*)&s_V[(bl * 8 + i_) * 68 + c];
        float ps[4]; *(float4*)ps = *(const float4*)&psc[c];   // uniform -> s_load
        float pf[4]; *(float4*)pf = *(const float4*)&psh[c];
        float w[6][4];
        #pragma unroll
        for (int d = 0; d < 6; d++) *(float4*)w[d] = *(const float4*)&p2t[d * 64 + c];
        #pragma unroll
        for (int jj = 0; jj < 2; jj++) {
            float uu[4]; *(float4*)uu = *(const float4*)&s_U[(bl * 8 + j0 + jj) * 68 + c];
            float p[4];
            #pragma unroll
            for (int q = 0; q < 4; q++) p[q] = fmaxf(ps[q] * (uu[q] + vv[q]) + pf[q], 0.f);
            #pragma unroll
            for (int d = 0; d < 6; d++)
                acc[jj][d] += p[0] * w[d][0] + p[1] * w[d][1] + p[2] * w[d][2] + p[3] * w[d][3];
        }
    }
    __syncthreads();                  // all GEMM reads of s_U/s_V complete
    float* s_out = s_V;               // overlay, stride 48
    float b2[6];
    #pragma unroll
    for (int d = 0; d < 6; d++) b2[d] = po2_b[d];
    #pragma unroll
    for (int jj = 0; jj < 2; jj++)
        #pragma unroll
        for (int d = 0; d < 6; d++)
            s_out[(bl * 8 + i_) * 48 + (j0 + jj) * 6 + d] = acc[jj][d] + b2[d];
    __syncthreads();

    if (t < 64) {
        const float* ws_mu = ws + WS_MU;
        const float* ws_sig = ws + WS_SIG;
        int grow = (b0 + (t >> 3)) * 8 + (t & 7);
        float s = 0.f;
        #pragma unroll
        for (int m4 = 0; m4 < 6; m4++) {
            float mu0[4]; *(float4*)mu0 = *(const float4*)&ws_mu[(size_t)grow * 24 + m4 * 4];
            float sg0[4]; *(float4*)sg0 = *(const float4*)&ws_sig[(size_t)grow * 24 + m4 * 4];
            #pragma unroll
            for (int q = 0; q < 4; q++) {
                int m = m4 * 4 + q;
                float mu1 = s_out[t * 48 + m];
                float sg1 = fmaxf(__expf(s_out[t * 48 + 24 + m]), 0.2f);
                float d0 = mu0[q] - mu1;
                s += __logf(sg1 / sg0[q]) + (sg0[q] + d0 * d0) / sg1 - 1.f;
            }
        }
        s_kl[t] = s;
    }
    __syncthreads();
    if (t < 8) {
        float s = 0.f;
        #pragma unroll
        for (int i = 0; i < 8; i++) s += s_kl[t * 8 + i];
        kl_out[b0 + t] = s * (0.5f / 192.f);
    }
}

// ---------------------------------------------------------------------------
extern "C" void kernel_launch(void* const* d_in, const int* in_sizes, int n_in,
                              void* d_out, int out_size, void* d_ws, size_t ws_size,
                              hipStream_t stream)
{
    (void)in_sizes; (void)n_in; (void)out_size; (void)ws_size;
    const float* inp   = (const float*)d_in[0];
    const float* hin   = (const float*)d_in[1];
    const float* noise = (const float*)d_in[2];
    const float* fc1_w = (const float*)d_in[3];
    const float* fc1_b = (const float*)d_in[4];
    const float* w_ih  = (const float*)d_in[5];
    const float* w_hh  = (const float*)d_in[6];
    const float* b_ih  = (const float*)d_in[7];
    const float* b_hh  = (const float*)d_in[8];
    const float* aw1_w = (const float*)d_in[9];
    const float* aw1_b = (const float*)d_in[10];
    const float* aw_g  = (const float*)d_in[11];
    const float* aw_be = (const float*)d_in[12];
    const float* aw2_w = (const float*)d_in[13];
    const float* aw2_b = (const float*)d_in[14];
    const float* po1_w = (const float*)d_in[15];
    const float* po1_b = (const float*)d_in[16];
    const float* po_g  = (const float*)d_in[17];
    const float* po_be = (const float*)d_in[18];
    const float* po2_w = (const float*)d_in[19];
    const float* po2_b = (const float*)d_in[20];
    const float* fc2_w = (const float*)d_in[21];
    const float* fc2_b = (const float*)d_in[22];
    float* out = (float*)d_out;
    float* ws  = (float*)d_ws;

    hipLaunchKernelGGL(k_prep,  dim3(8),    dim3(256), 0, stream,
                       fc1_w, w_ih, w_hh, aw1_w, po1_w, ws);
    hipLaunchKernelGGL(k_front, dim3(1024), dim3(256), 0, stream,
                       inp, hin, fc1_b, b_ih, b_hh, aw1_b, out + OUT_H, ws);
    hipLaunchKernelGGL(k_stats, dim3(1),    dim3(128), 0, stream,
                       aw_g, aw_be, po_g, po_be, po1_b, po2_w, ws);
    hipLaunchKernelGGL(k_aw,    dim3(2048), dim3(256), 0, stream,
                       ws, out + OUT_H, noise, aw2_w, aw2_b, fc2_w, fc2_b, out);
    hipLaunchKernelGGL(k_po,    dim3(1024), dim3(256), 0, stream,
                       ws, po2_b, out + OUT_KL);
}

// Round 5
// 211.497 us; speedup vs baseline: 1.8139x; 1.3599x over previous
//
#include <hip/hip_runtime.h>
#include <math.h>

// ---------------------------------------------------------------------------
// Problem constants
// ---------------------------------------------------------------------------
#define NROWS 65536          // B*NAG = 8192*8
#define NB    8192           // B
// workspace layout (float offsets) -- no more big activation buffers
#define STAT_OFF  0          // 448 floats: asum asq usum usq vsum vsq cross
#define DERIV_OFF 448        // 640: ascale ashift pscale pshift | po2^T [6][64]
#define WPACK_OFF 1088       // 5952 frags x 8 ushort = 47616 ushorts
// d_out layout (float offsets): x_out, h, KL
#define OUT_XOUT 0
#define OUT_H    917504
#define OUT_KL   5111808

typedef __attribute__((ext_vector_type(8))) short bhalf8;
typedef __attribute__((ext_vector_type(4))) float floatx4;
typedef __attribute__((ext_vector_type(4))) unsigned short u16x4;

__device__ __forceinline__ float sigmf(float x) { return 1.0f / (1.0f + __expf(-x)); }
__device__ __forceinline__ float tanhfast(float x) {
    x = fminf(fmaxf(x, -15.f), 15.f);
    float e = __expf(-2.f * x);
    return (1.f - e) / (1.f + e);
}
__device__ __forceinline__ unsigned short f2bf(float f) {   // RNE fp32->bf16
    unsigned int u = __float_as_uint(f);
    u += 0x7FFFu + ((u >> 16) & 1u);
    return (unsigned short)(u >> 16);
}
__device__ __forceinline__ float bf2f(unsigned short s) {
    return __uint_as_float(((unsigned int)s) << 16);
}

// ---------------------------------------------------------------------------
// K0 (k_prep): zero stat accumulators + pack ALL weights into bf16 MFMA
// B-fragment order.  Fragment = 16 cols x 32 k; lane (n=lane&15, quad=lane>>4)
// holds 8 contiguous bf16 for k = quad*8+j.
//   wp1  [   0..767 ]: fc1_w [96][64]      4 ntile x 3 kchunk
//   wp2  [ 768..3839]: w_ih|w_hh [64][192] 24 ntile x 2 kchunk
//                      t0-3 ir, 4-7 iz, 8-11 in, 12-15 hr, 16-19 hz, 20-23 hn
//   wp3  [3840..5375]: aw1_w | po1_w[:64] | po1_w[64:]  12 ntile x 2 kchunk
//   wpa2 [5376..5759]: aw2_w [64][48]      3 ntile x 2 kchunk
//   wpf2 [5760..5951]: fc2_w [88][14] zero-padded to [96][16]  1 ntile x 3 k
// ---------------------------------------------------------------------------
__global__ void k_prep(const float* __restrict__ fc1_w,
                       const float* __restrict__ w_ih, const float* __restrict__ w_hh,
                       const float* __restrict__ aw1_w, const float* __restrict__ po1_w,
                       const float* __restrict__ aw2_w, const float* __restrict__ fc2_w,
                       float* __restrict__ ws)
{
    const int t = threadIdx.x;
    if (blockIdx.x == 0)
        for (int i = t; i < 448; i += 256) ws[STAT_OFF + i] = 0.f;

    unsigned short* wpk = (unsigned short*)(ws + WPACK_OFF);
    for (int f = blockIdx.x * 256 + t; f < 5952; f += gridDim.x * 256) {
        int lane, c, tile;
        const float* src;
        int colbase, krowstride, kofs, kmax = 1 << 30, colmax = 16;
        if (f < 768) {            // wp1
            tile = f / 192; c = (f % 192) / 64; lane = f % 64;
            src = fc1_w; krowstride = 64; colbase = tile * 16; kofs = 0;
        } else if (f < 3840) {    // wp2
            int f2 = f - 768;
            tile = f2 / 128; c = (f2 % 128) / 64; lane = f2 % 64;
            if (tile < 12) { src = w_ih; colbase = tile * 16; }
            else           { src = w_hh; colbase = (tile - 12) * 16; }
            krowstride = 192; kofs = 0;
        } else if (f < 5376) {    // wp3
            int f3 = f - 3840;
            tile = f3 / 128; c = (f3 % 128) / 64; lane = f3 % 64;
            if (tile < 4)       { src = aw1_w; colbase = tile * 16; kofs = 0; }
            else if (tile < 8)  { src = po1_w; colbase = (tile - 4) * 16; kofs = 0; }
            else                { src = po1_w; colbase = (tile - 8) * 16; kofs = 64; }
            krowstride = 64;
        } else if (f < 5760) {    // wpa2
            int f4 = f - 5376;
            tile = f4 / 128; c = (f4 % 128) / 64; lane = f4 % 64;
            src = aw2_w; krowstride = 48; colbase = tile * 16; kofs = 0;
        } else {                  // wpf2
            int f5 = f - 5760;
            c = f5 / 64; lane = f5 % 64;
            src = fc2_w; krowstride = 14; colbase = 0; kofs = 0;
            kmax = 88; colmax = 14;
        }
        int n = lane & 15, quad = lane >> 4;
        int col = colbase + n;
        unsigned short o[8];
        #pragma unroll
        for (int j = 0; j < 8; j++) {
            int k = c * 32 + quad * 8 + j + kofs;
            float v = (k < kmax && n < colmax) ? src[(size_t)k * krowstride + col] : 0.f;
            o[j] = f2bf(v);
        }
        u16x4 lo, hi;
        lo.x = o[0]; lo.y = o[1]; lo.z = o[2]; lo.w = o[3];
        hi.x = o[4]; hi.y = o[5]; hi.z = o[6]; hi.w = o[7];
        *(u16x4*)&wpk[f * 8]     = lo;
        *(u16x4*)&wpk[f * 8 + 4] = hi;
    }
}

// ---------------------------------------------------------------------------
// K1: fc1 -> GRU -> h + BN stat partials (a1/U/V computed but NOT stored).
// 64 rows/block, 256 thr (4 waves x 16 rows), bf16 MFMA 16x16x32.
// P2 uses 16 accumulators: MFMA chains gi_r+gh_r into one register.
// ---------------------------------------------------------------------------
__global__ __launch_bounds__(256) void k_front(
    const float* __restrict__ inp, const float* __restrict__ hin,
    const float* __restrict__ fc1_b,
    const float* __restrict__ b_ih, const float* __restrict__ b_hh,
    const float* __restrict__ aw1_b,
    float* __restrict__ h_out, float* __restrict__ ws)
{
    __shared__ __align__(16) unsigned short s_inpb[64 * 104]; // inp; later h (stride 88)
    __shared__ __align__(16) unsigned short s_hinb[64 * 88];
    __shared__ __align__(16) unsigned short s_xb[64 * 88];
    __shared__ float s_stat[448];

    const int t = threadIdx.x;
    const int row0 = blockIdx.x * 64;
    const int lane = t & 63;
    const int w = t >> 6;
    const int n16 = lane & 15;
    const int quad = lane >> 4;
    const int mrow = w * 16 + n16;

    {
        const float* gi = inp + (size_t)row0 * 96;
        for (int i = t; i < 1536; i += 256) {
            int r = i / 24, c4 = (i - r * 24) * 4;
            float4 v = *(const float4*)&gi[r * 96 + c4];
            u16x4 p; p.x = f2bf(v.x); p.y = f2bf(v.y); p.z = f2bf(v.z); p.w = f2bf(v.w);
            *(u16x4*)&s_inpb[r * 104 + c4] = p;
        }
        const float* gh = hin + (size_t)row0 * 64;
        for (int i = t; i < 1024; i += 256) {
            int r = i >> 4, c4 = (i & 15) * 4;
            float4 v = *(const float4*)&gh[r * 64 + c4];
            u16x4 p; p.x = f2bf(v.x); p.y = f2bf(v.y); p.z = f2bf(v.z); p.w = f2bf(v.w);
            *(u16x4*)&s_hinb[r * 88 + c4] = p;
        }
    }
    for (int i = t; i < 448; i += 256) s_stat[i] = 0.f;
    __syncthreads();

    const bhalf8* wp1 = (const bhalf8*)((const unsigned short*)(ws + WPACK_OFF));
    const bhalf8* wp2 = wp1 + 768;
    const bhalf8* wp3 = wp1 + 3840;

    // ---- P1: x = relu(inp @ fc1_w + b) ----
    {
        bhalf8 ai0 = *(const bhalf8*)&s_inpb[mrow * 104 + 0  + quad * 8];
        bhalf8 ai1 = *(const bhalf8*)&s_inpb[mrow * 104 + 32 + quad * 8];
        bhalf8 ai2 = *(const bhalf8*)&s_inpb[mrow * 104 + 64 + quad * 8];
        #pragma unroll
        for (int g = 0; g < 4; g++) {
            floatx4 d = {0.f, 0.f, 0.f, 0.f};
            d = __builtin_amdgcn_mfma_f32_16x16x32_bf16(ai0, wp1[(g * 3 + 0) * 64 + lane], d, 0, 0, 0);
            d = __builtin_amdgcn_mfma_f32_16x16x32_bf16(ai1, wp1[(g * 3 + 1) * 64 + lane], d, 0, 0, 0);
            d = __builtin_amdgcn_mfma_f32_16x16x32_bf16(ai2, wp1[(g * 3 + 2) * 64 + lane], d, 0, 0, 0);
            int col = g * 16 + n16;
            float bb = fc1_b[col];
            #pragma unroll
            for (int q = 0; q < 4; q++) {
                float xv = fmaxf(d[q] + bb, 0.f);
                s_xb[(w * 16 + quad * 4 + q) * 88 + col] = f2bf(xv);
            }
        }
    }
    // own-wave rows only -> no barrier before P2 A-frag reads

    // ---- P2 MFMA: gr = x@wih_r + h@whh_r (chained), gz likewise, gn, gh2 ----
    floatx4 gr[4], gz[4], gn[4], gh2[4];
    {
        bhalf8 ax0 = *(const bhalf8*)&s_xb[mrow * 88 + 0  + quad * 8];
        bhalf8 ax1 = *(const bhalf8*)&s_xb[mrow * 88 + 32 + quad * 8];
        bhalf8 ah0 = *(const bhalf8*)&s_hinb[mrow * 88 + 0  + quad * 8];
        bhalf8 ah1 = *(const bhalf8*)&s_hinb[mrow * 88 + 32 + quad * 8];
        #pragma unroll
        for (int g = 0; g < 4; g++) {
            floatx4 d = {0.f, 0.f, 0.f, 0.f};
            d = __builtin_amdgcn_mfma_f32_16x16x32_bf16(ax0, wp2[((0 + g) * 2 + 0) * 64 + lane], d, 0, 0, 0);
            d = __builtin_amdgcn_mfma_f32_16x16x32_bf16(ax1, wp2[((0 + g) * 2 + 1) * 64 + lane], d, 0, 0, 0);
            d = __builtin_amdgcn_mfma_f32_16x16x32_bf16(ah0, wp2[((12 + g) * 2 + 0) * 64 + lane], d, 0, 0, 0);
            d = __builtin_amdgcn_mfma_f32_16x16x32_bf16(ah1, wp2[((12 + g) * 2 + 1) * 64 + lane], d, 0, 0, 0);
            gr[g] = d;
            floatx4 e = {0.f, 0.f, 0.f, 0.f};
            e = __builtin_amdgcn_mfma_f32_16x16x32_bf16(ax0, wp2[((4 + g) * 2 + 0) * 64 + lane], e, 0, 0, 0);
            e = __builtin_amdgcn_mfma_f32_16x16x32_bf16(ax1, wp2[((4 + g) * 2 + 1) * 64 + lane], e, 0, 0, 0);
            e = __builtin_amdgcn_mfma_f32_16x16x32_bf16(ah0, wp2[((16 + g) * 2 + 0) * 64 + lane], e, 0, 0, 0);
            e = __builtin_amdgcn_mfma_f32_16x16x32_bf16(ah1, wp2[((16 + g) * 2 + 1) * 64 + lane], e, 0, 0, 0);
            gz[g] = e;
            floatx4 p = {0.f, 0.f, 0.f, 0.f};
            p = __builtin_amdgcn_mfma_f32_16x16x32_bf16(ax0, wp2[((8 + g) * 2 + 0) * 64 + lane], p, 0, 0, 0);
            p = __builtin_amdgcn_mfma_f32_16x16x32_bf16(ax1, wp2[((8 + g) * 2 + 1) * 64 + lane], p, 0, 0, 0);
            gn[g] = p;
            floatx4 s = {0.f, 0.f, 0.f, 0.f};
            s = __builtin_amdgcn_mfma_f32_16x16x32_bf16(ah0, wp2[((20 + g) * 2 + 0) * 64 + lane], s, 0, 0, 0);
            s = __builtin_amdgcn_mfma_f32_16x16x32_bf16(ah1, wp2[((20 + g) * 2 + 1) * 64 + lane], s, 0, 0, 0);
            gh2[g] = s;
        }
    }
    __syncthreads();   // P1/P2 LDS reads done before s_hb overlays s_inpb

    // ---- P2 post: gates -> h ----
    unsigned short* s_hb = s_inpb;   // stride 88
    #pragma unroll
    for (int g = 0; g < 4; g++) {
        int col = g * 16 + n16;
        float br_ = b_ih[col] + b_hh[col];
        float bz_ = b_ih[64 + col] + b_hh[64 + col];
        float bin_ = b_ih[128 + col];
        float bhn_ = b_hh[128 + col];
        #pragma unroll
        for (int q = 0; q < 4; q++) {
            int lrow = w * 16 + quad * 4 + q;
            size_t grow = (size_t)(row0 + lrow);
            float r  = sigmf(gr[g][q] + br_);
            float z  = sigmf(gz[g][q] + bz_);
            float nt = tanhfast(gn[g][q] + bin_ + r * (gh2[g][q] + bhn_));
            float hp = hin[grow * 64 + col];
            float h  = (1.f - z) * nt + z * hp;
            h_out[grow * 64 + col] = h;
            s_hb[lrow * 88 + col] = f2bf(h);
        }
    }
    // own-wave rows only -> no barrier before P3 A-frag reads

    // ---- P3 MFMA: a1/U/V (stats only, values discarded) ----
    {
        bhalf8 ah0 = *(const bhalf8*)&s_hb[mrow * 88 + 0  + quad * 8];
        bhalf8 ah1 = *(const bhalf8*)&s_hb[mrow * 88 + 32 + quad * 8];
        floatx4 g3[12];
        #pragma unroll
        for (int tt = 0; tt < 12; tt++) {
            floatx4 d = {0.f, 0.f, 0.f, 0.f};
            d = __builtin_amdgcn_mfma_f32_16x16x32_bf16(ah0, wp3[(tt * 2 + 0) * 64 + lane], d, 0, 0, 0);
            d = __builtin_amdgcn_mfma_f32_16x16x32_bf16(ah1, wp3[(tt * 2 + 1) * 64 + lane], d, 0, 0, 0);
            g3[tt] = d;
        }
        #pragma unroll
        for (int g = 0; g < 4; g++) {
            int col = g * 16 + n16;
            float ab = aw1_b[col];
            float s1 = 0.f, s2 = 0.f;
            #pragma unroll
            for (int q = 0; q < 4; q++) {
                float v = g3[g][q] + ab;
                s1 += v; s2 += v * v;
            }
            float t1 = s1 + __shfl_xor(s1, 16, 64); t1 += __shfl_xor(t1, 32, 64);
            float t2 = s2 + __shfl_xor(s2, 16, 64); t2 += __shfl_xor(t2, 32, 64);
            if (quad == 0) {
                atomicAdd(&s_stat[col], t1);
                atomicAdd(&s_stat[64 + col], t2);
            }
        }
        #pragma unroll
        for (int g = 0; g < 4; g++) {
            int col = g * 16 + n16;
            float su = 0.f, suq = 0.f, sv = 0.f, svq = 0.f;
            #pragma unroll
            for (int q = 0; q < 4; q++) {
                float uv = g3[4 + g][q]; su += uv; suq += uv * uv;
                float vv = g3[8 + g][q]; sv += vv; svq += vv * vv;
            }
            float u8 = su + __shfl_xor(su, 16, 64);
            float v8 = sv + __shfl_xor(sv, 16, 64);
            if ((quad & 1) == 0)          // quad 0: rows 0-7 group; quad 2: rows 8-15
                atomicAdd(&s_stat[384 + col], u8 * v8 * (1.f / 64.f));
            float su16 = u8 + __shfl_xor(u8, 32, 64);
            float sv16 = v8 + __shfl_xor(v8, 32, 64);
            float suq16 = suq + __shfl_xor(suq, 16, 64); suq16 += __shfl_xor(suq16, 32, 64);
            float svq16 = svq + __shfl_xor(svq, 16, 64); svq16 += __shfl_xor(svq16, 32, 64);
            if (quad == 0) {
                atomicAdd(&s_stat[128 + col], su16);
                atomicAdd(&s_stat[192 + col], suq16);
                atomicAdd(&s_stat[256 + col], sv16);
                atomicAdd(&s_stat[320 + col], svq16);
            }
        }
    }
    __syncthreads();
    if (t < 64) {
        float* gs = ws + STAT_OFF;
        #pragma unroll
        for (int q = 0; q < 7; q++)
            atomicAdd(&gs[q * 64 + t], s_stat[q * 64 + t]);
    }
}

// ---------------------------------------------------------------------------
// K2: finalize BN scale/shift.  Var(U+V) = Var_u + Var_v + 2*(cross/B - Eu*Ev)
// ---------------------------------------------------------------------------
__global__ void k_stats(const float* __restrict__ aw_g, const float* __restrict__ aw_be,
                        const float* __restrict__ po_g, const float* __restrict__ po_be,
                        const float* __restrict__ po1_b, const float* __restrict__ po2_w,
                        float* __restrict__ ws)
{
    const int t = threadIdx.x;
    const float* st = ws + STAT_OFF;
    float* dv = ws + DERIV_OFF;
    if (t < 64) {
        const float invN = 1.f / 65536.f;
        float am = st[t] * invN;
        float av = st[64 + t] * invN - am * am;
        float asc = aw_g[t] * rsqrtf(av + 1e-5f);
        dv[t] = asc;
        dv[64 + t] = aw_be[t] - asc * am;
        float Eu = st[128 + t] * invN;
        float vu = st[192 + t] * invN - Eu * Eu;
        float Ev = st[256 + t] * invN;
        float vv = st[320 + t] * invN - Ev * Ev;
        float cov = st[384 + t] * (1.f / 8192.f) - Eu * Ev;
        float my = Eu + Ev + po1_b[t];
        float vy = vu + vv + 2.f * cov;
        float psc = po_g[t] * rsqrtf(vy + 1e-5f);
        dv[128 + t] = psc;
        dv[192 + t] = po_be[t] + psc * (po1_b[t] - my);
    }
    for (int i = t; i < 384; i += 128) {
        int d = i >> 6, c = i & 63;
        dv[256 + i] = po2_w[c * 6 + d];     // po2^T [6][64]
    }
}

// ---------------------------------------------------------------------------
// K3 (k_heads): fused actor + critic head.  32 rows (4 b) per block, 128 thr
// (2 waves x 16 rows).  Recomputes a1/U/V from h via MFMA (bit-identical to
// K1's stat inputs), keeps everything in LDS; reads only h + noise, writes
// x_out + KL.  LDS ~27.6 KB -> 5 blocks/CU.
// ---------------------------------------------------------------------------
__global__ __launch_bounds__(128) void k_heads(
    const float* __restrict__ h_glob, const float* __restrict__ noise,
    const float* __restrict__ aw1_b, const float* __restrict__ aw2_b,
    const float* __restrict__ fc2_b, const float* __restrict__ po2_b,
    const float* __restrict__ ws, float* __restrict__ out)
{
    __shared__ __align__(16) unsigned short s_hb[32 * 104]; // h | c | zero-pad
    __shared__ __align__(16) unsigned short s_U[32 * 72];
    __shared__ __align__(16) unsigned short s_V[32 * 72];
    __shared__ float s_ms[32 * 48];                         // mu | sigma
    __shared__ __align__(16) float s_u2[32 * 48];           // s_ab (bf16) then s_out
    __shared__ float s_kl[32];

    const int t = threadIdx.x;
    const int row0 = blockIdx.x * 32;
    const int b0 = blockIdx.x * 4;
    const int lane = t & 63;
    const int w = t >> 6;
    const int n16 = lane & 15;
    const int quad = lane >> 4;
    const int mrow = w * 16 + n16;
    const float* dv = ws + DERIV_OFF;

    // ---- stage h -> bf16 (cols 0-63); zero pad cols 88-95 ----
    {
        const float* gh = h_glob + (size_t)row0 * 64;
        for (int i = t; i < 512; i += 128) {
            int r = i >> 4, c4 = (i & 15) * 4;
            float4 v = *(const float4*)&gh[r * 64 + c4];
            u16x4 p; p.x = f2bf(v.x); p.y = f2bf(v.y); p.z = f2bf(v.z); p.w = f2bf(v.w);
            *(u16x4*)&s_hb[r * 104 + c4] = p;
        }
        for (int i = t; i < 64; i += 128) {
            int r = i >> 1, c4 = 88 + (i & 1) * 4;
            u16x4 z; z.x = 0; z.y = 0; z.z = 0; z.w = 0;
            *(u16x4*)&s_hb[r * 104 + c4] = z;
        }
    }
    __syncthreads();

    const bhalf8* wp3  = ((const bhalf8*)((const unsigned short*)(ws + WPACK_OFF))) + 3840;
    const bhalf8* wpa2 = wp3 + 1536;
    const bhalf8* wpf2 = wpa2 + 384;
    unsigned short* s_ab = (unsigned short*)s_u2;    // stride 72

    // ---- phase A: a1/U/V via MFMA ----
    {
        bhalf8 ah0 = *(const bhalf8*)&s_hb[mrow * 104 + 0  + quad * 8];
        bhalf8 ah1 = *(const bhalf8*)&s_hb[mrow * 104 + 32 + quad * 8];
        floatx4 g3[12];
        #pragma unroll
        for (int tt = 0; tt < 12; tt++) {
            floatx4 d = {0.f, 0.f, 0.f, 0.f};
            d = __builtin_amdgcn_mfma_f32_16x16x32_bf16(ah0, wp3[(tt * 2 + 0) * 64 + lane], d, 0, 0, 0);
            d = __builtin_amdgcn_mfma_f32_16x16x32_bf16(ah1, wp3[(tt * 2 + 1) * 64 + lane], d, 0, 0, 0);
            g3[tt] = d;
        }
        #pragma unroll
        for (int g = 0; g < 4; g++) {
            int col = g * 16 + n16;
            float ab = aw1_b[col];
            float sc = dv[col], sf = dv[64 + col];
            #pragma unroll
            for (int q = 0; q < 4; q++) {
                int lrow = w * 16 + quad * 4 + q;
                float a = fmaxf(sc * (g3[g][q] + ab) + sf, 0.f);
                s_ab[lrow * 72 + col] = f2bf(a);
                s_U[lrow * 72 + col] = f2bf(g3[4 + g][q]);
                s_V[lrow * 72 + col] = f2bf(g3[8 + g][q]);
            }
        }
    }
    __syncthreads();

    // ---- phase B1: aw = a @ aw2_w + b -> mu / sigma ----
    {
        bhalf8 aa0 = *(const bhalf8*)&s_ab[mrow * 72 + 0  + quad * 8];
        bhalf8 aa1 = *(const bhalf8*)&s_ab[mrow * 72 + 32 + quad * 8];
        #pragma unroll
        for (int g = 0; g < 3; g++) {
            floatx4 d = {0.f, 0.f, 0.f, 0.f};
            d = __builtin_amdgcn_mfma_f32_16x16x32_bf16(aa0, wpa2[(g * 2 + 0) * 64 + lane], d, 0, 0, 0);
            d = __builtin_amdgcn_mfma_f32_16x16x32_bf16(aa1, wpa2[(g * 2 + 1) * 64 + lane], d, 0, 0, 0);
            int col = g * 16 + n16;
            float bb = aw2_b[col];
            #pragma unroll
            for (int q = 0; q < 4; q++) {
                int lrow = w * 16 + quad * 4 + q;
                float v = d[q] + bb;
                s_ms[lrow * 48 + col] = (col < 24) ? v : fmaxf(__expf(v), 0.2f);
            }
        }
    }
    __syncthreads();

    // ---- phase B2: c = mu + sqrt(sigma)*noise -> s_hb cols 64-87 (bf16) ----
    for (int i = t; i < 768; i += 128) {
        int r = i / 24, m = i - r * 24;
        float c = s_ms[r * 48 + m] + sqrtf(s_ms[r * 48 + 24 + m]) * noise[(size_t)(row0 + r) * 24 + m];
        s_hb[r * 104 + 64 + m] = f2bf(c);
    }
    __syncthreads();

    // ---- phase B3: x_out = [h,c] @ fc2_w + b ----
    {
        bhalf8 hc0 = *(const bhalf8*)&s_hb[mrow * 104 + 0  + quad * 8];
        bhalf8 hc1 = *(const bhalf8*)&s_hb[mrow * 104 + 32 + quad * 8];
        bhalf8 hc2 = *(const bhalf8*)&s_hb[mrow * 104 + 64 + quad * 8];
        floatx4 d = {0.f, 0.f, 0.f, 0.f};
        d = __builtin_amdgcn_mfma_f32_16x16x32_bf16(hc0, wpf2[0 * 64 + lane], d, 0, 0, 0);
        d = __builtin_amdgcn_mfma_f32_16x16x32_bf16(hc1, wpf2[1 * 64 + lane], d, 0, 0, 0);
        d = __builtin_amdgcn_mfma_f32_16x16x32_bf16(hc2, wpf2[2 * 64 + lane], d, 0, 0, 0);
        if (n16 < 14) {
            float bb = fc2_b[n16];
            float* xout = out + OUT_XOUT;
            #pragma unroll
            for (int q = 0; q < 4; q++) {
                size_t grow = (size_t)(row0 + w * 16 + quad * 4 + q);
                xout[grow * 14 + n16] = d[q] + bb;
            }
        }
    }
    __syncthreads();   // s_hb / s_ab dead; s_out overlay + critic reads ready

    // ---- phase C: critic pairwise + po2 ----
    float* s_out = s_u2;               // stride 48
    {
        const float* psc = dv + 128;
        const float* psh = dv + 192;
        const float* p2t = dv + 256;   // [6][64]
        const int bl = t >> 5;         // local b (0..3)
        const int rem = t & 31;
        const int i_ = rem >> 2;       // i (0..7)
        const int j0 = (rem & 3) * 2;  // j base
        float acc[2][6];
        #pragma unroll
        for (int jj = 0; jj < 2; jj++)
            #pragma unroll
            for (int d = 0; d < 6; d++) acc[jj][d] = 0.f;

        for (int c = 0; c < 64; c += 4) {
            u16x4 vb = *(const u16x4*)&s_V[(bl * 8 + i_) * 72 + c];
            float vv[4] = {bf2f(vb.x), bf2f(vb.y), bf2f(vb.z), bf2f(vb.w)};
            float ps[4]; *(float4*)ps = *(const float4*)&psc[c];
            float pf[4]; *(float4*)pf = *(const float4*)&psh[c];
            float wv[6][4];
            #pragma unroll
            for (int d = 0; d < 6; d++) *(float4*)wv[d] = *(const float4*)&p2t[d * 64 + c];
            #pragma unroll
            for (int jj = 0; jj < 2; jj++) {
                u16x4 ub = *(const u16x4*)&s_U[(bl * 8 + j0 + jj) * 72 + c];
                float p[4];
                p[0] = fmaxf(ps[0] * (bf2f(ub.x) + vv[0]) + pf[0], 0.f);
                p[1] = fmaxf(ps[1] * (bf2f(ub.y) + vv[1]) + pf[1], 0.f);
                p[2] = fmaxf(ps[2] * (bf2f(ub.z) + vv[2]) + pf[2], 0.f);
                p[3] = fmaxf(ps[3] * (bf2f(ub.w) + vv[3]) + pf[3], 0.f);
                #pragma unroll
                for (int d = 0; d < 6; d++)
                    acc[jj][d] += p[0] * wv[d][0] + p[1] * wv[d][1] + p[2] * wv[d][2] + p[3] * wv[d][3];
            }
        }
        #pragma unroll
        for (int jj = 0; jj < 2; jj++)
            #pragma unroll
            for (int d = 0; d < 6; d++)
                s_out[(bl * 8 + i_) * 48 + (j0 + jj) * 6 + d] = acc[jj][d] + po2_b[d];
    }
    __syncthreads();

    // ---- KL ----
    if (t < 32) {
        float s = 0.f;
        #pragma unroll 4
        for (int m = 0; m < 24; m++) {
            float mu0 = s_ms[t * 48 + m];
            float sg0 = s_ms[t * 48 + 24 + m];
            float mu1 = s_out[t * 48 + m];
            float sg1 = fmaxf(__expf(s_out[t * 48 + 24 + m]), 0.2f);
            float d0 = mu0 - mu1;
            s += __logf(sg1 / sg0) + (sg0 + d0 * d0) / sg1 - 1.f;
        }
        s_kl[t] = s;
    }
    __syncthreads();
    if (t < 4) {
        float s = 0.f;
        #pragma unroll
        for (int i = 0; i < 8; i++) s += s_kl[t * 8 + i];
        out[OUT_KL + b0 + t] = s * (0.5f / 192.f);
    }
}

// ---------------------------------------------------------------------------
extern "C" void kernel_launch(void* const* d_in, const int* in_sizes, int n_in,
                              void* d_out, int out_size, void* d_ws, size_t ws_size,
                              hipStream_t stream)
{
    (void)in_sizes; (void)n_in; (void)out_size; (void)ws_size;
    const float* inp   = (const float*)d_in[0];
    const float* hin   = (const float*)d_in[1];
    const float* noise = (const float*)d_in[2];
    const float* fc1_w = (const float*)d_in[3];
    const float* fc1_b = (const float*)d_in[4];
    const float* w_ih  = (const float*)d_in[5];
    const float* w_hh  = (const float*)d_in[6];
    const float* b_ih  = (const float*)d_in[7];
    const float* b_hh  = (const float*)d_in[8];
    const float* aw1_w = (const float*)d_in[9];
    const float* aw1_b = (const float*)d_in[10];
    const float* aw_g  = (const float*)d_in[11];
    const float* aw_be = (const float*)d_in[12];
    const float* aw2_w = (const float*)d_in[13];
    const float* aw2_b = (const float*)d_in[14];
    const float* po1_w = (const float*)d_in[15];
    const float* po1_b = (const float*)d_in[16];
    const float* po_g  = (const float*)d_in[17];
    const float* po_be = (const float*)d_in[18];
    const float* po2_w = (const float*)d_in[19];
    const float* po2_b = (const float*)d_in[20];
    const float* fc2_w = (const float*)d_in[21];
    const float* fc2_b = (const float*)d_in[22];
    float* out = (float*)d_out;
    float* ws  = (float*)d_ws;

    hipLaunchKernelGGL(k_prep,  dim3(8),    dim3(256), 0, stream,
                       fc1_w, w_ih, w_hh, aw1_w, po1_w, aw2_w, fc2_w, ws);
    hipLaunchKernelGGL(k_front, dim3(1024), dim3(256), 0, stream,
                       inp, hin, fc1_b, b_ih, b_hh, aw1_b, out + OUT_H, ws);
    hipLaunchKernelGGL(k_stats, dim3(1),    dim3(128), 0, stream,
                       aw_g, aw_be, po_g, po_be, po1_b, po2_w, ws);
    hipLaunchKernelGGL(k_heads, dim3(2048), dim3(128), 0, stream,
                       out + OUT_H, noise, aw1_b, aw2_b, fc2_b, po2_b, ws, out);
}

// Round 6
// 197.697 us; speedup vs baseline: 1.9405x; 1.0698x over previous
//
#include <hip/hip_runtime.h>
#include <math.h>

// ---------------------------------------------------------------------------
// Problem constants
// ---------------------------------------------------------------------------
#define NROWS 65536          // B*NAG = 8192*8
#define NB    8192           // B
// workspace layout (float offsets)
#define STAT_OFF  0          // 448 floats: asum asq usum usq vsum vsq cross
#define WPACK_OFF 448        // 5952 frags x 8 ushort = 47616 ushorts
// d_out layout (float offsets): x_out, h, KL
#define OUT_XOUT 0
#define OUT_H    917504
#define OUT_KL   5111808

typedef __attribute__((ext_vector_type(8))) short bhalf8;
typedef __attribute__((ext_vector_type(4))) float floatx4;
typedef __attribute__((ext_vector_type(4))) unsigned short u16x4;

__device__ __forceinline__ float sigmf(float x) { return 1.0f / (1.0f + __expf(-x)); }
__device__ __forceinline__ float tanhfast(float x) {
    x = fminf(fmaxf(x, -15.f), 15.f);
    float e = __expf(-2.f * x);
    return (1.f - e) / (1.f + e);
}
__device__ __forceinline__ unsigned short f2bf(float f) {   // RNE fp32->bf16
    unsigned int u = __float_as_uint(f);
    u += 0x7FFFu + ((u >> 16) & 1u);
    return (unsigned short)(u >> 16);
}

// ---------------------------------------------------------------------------
// K0 (k_prep): zero stat accumulators + pack ALL weights into bf16 MFMA
// B-fragment order.  Fragment = 16 cols x 32 k; lane (n=lane&15, quad=lane>>4)
// holds 8 contiguous bf16 for k = quad*8+j.   24 blocks -> single pass.
//   wp1  [   0..767 ]: fc1_w [96][64]      4 ntile x 3 kchunk
//   wp2  [ 768..3839]: w_ih|w_hh [64][192] 24 ntile x 2 kchunk
//   wp3  [3840..5375]: aw1_w | po1_w[:64] | po1_w[64:]  12 ntile x 2 kchunk
//   wpa2 [5376..5759]: aw2_w [64][48]      3 ntile x 2 kchunk
//   wpf2 [5760..5951]: fc2_w [88][14] zero-padded to [96][16]  1 ntile x 3 k
// ---------------------------------------------------------------------------
__global__ void k_prep(const float* __restrict__ fc1_w,
                       const float* __restrict__ w_ih, const float* __restrict__ w_hh,
                       const float* __restrict__ aw1_w, const float* __restrict__ po1_w,
                       const float* __restrict__ aw2_w, const float* __restrict__ fc2_w,
                       float* __restrict__ ws)
{
    const int t = threadIdx.x;
    if (blockIdx.x == 0)
        for (int i = t; i < 448; i += 256) ws[STAT_OFF + i] = 0.f;

    unsigned short* wpk = (unsigned short*)(ws + WPACK_OFF);
    for (int f = blockIdx.x * 256 + t; f < 5952; f += gridDim.x * 256) {
        int lane, c, tile;
        const float* src;
        int colbase, krowstride, kofs = 0, kmax = 1 << 30, colmax = 16;
        if (f < 768) {            // wp1
            tile = f / 192; c = (f % 192) / 64; lane = f % 64;
            src = fc1_w; krowstride = 64; colbase = tile * 16;
        } else if (f < 3840) {    // wp2
            int f2 = f - 768;
            tile = f2 / 128; c = (f2 % 128) / 64; lane = f2 % 64;
            if (tile < 12) { src = w_ih; colbase = tile * 16; }
            else           { src = w_hh; colbase = (tile - 12) * 16; }
            krowstride = 192;
        } else if (f < 5376) {    // wp3
            int f3 = f - 3840;
            tile = f3 / 128; c = (f3 % 128) / 64; lane = f3 % 64;
            if (tile < 4)       { src = aw1_w; colbase = tile * 16; }
            else if (tile < 8)  { src = po1_w; colbase = (tile - 4) * 16; }
            else                { src = po1_w; colbase = (tile - 8) * 16; kofs = 64; }
            krowstride = 64;
        } else if (f < 5760) {    // wpa2
            int f4 = f - 5376;
            tile = f4 / 128; c = (f4 % 128) / 64; lane = f4 % 64;
            src = aw2_w; krowstride = 48; colbase = tile * 16;
        } else {                  // wpf2
            int f5 = f - 5760;
            c = f5 / 64; lane = f5 % 64;
            src = fc2_w; krowstride = 14; colbase = 0;
            kmax = 88; colmax = 14;
        }
        int n = lane & 15, quad = lane >> 4;
        int col = colbase + n;
        unsigned short o[8];
        #pragma unroll
        for (int j = 0; j < 8; j++) {
            int k = c * 32 + quad * 8 + j + kofs;
            float v = (k < kmax && n < colmax) ? src[(size_t)k * krowstride + col] : 0.f;
            o[j] = f2bf(v);
        }
        u16x4 lo, hi;
        lo.x = o[0]; lo.y = o[1]; lo.z = o[2]; lo.w = o[3];
        hi.x = o[4]; hi.y = o[5]; hi.z = o[6]; hi.w = o[7];
        *(u16x4*)&wpk[f * 8]     = lo;
        *(u16x4*)&wpk[f * 8 + 4] = hi;
    }
}

// ---------------------------------------------------------------------------
// K1: fc1 -> GRU -> h + BN stat partials (a1/U/V values discarded).
// 128 rows/block, 256 thr (4 waves), 2 m-tiles (32 rows) per wave so each
// weight fragment load feeds 2 MFMAs.  512 blocks.  LDS ~71.8 KB -> 2/CU.
// ---------------------------------------------------------------------------
__global__ __launch_bounds__(256, 2) void k_front(
    const float* __restrict__ inp, const float* __restrict__ hin,
    const float* __restrict__ fc1_b,
    const float* __restrict__ b_ih, const float* __restrict__ b_hh,
    const float* __restrict__ aw1_b,
    float* __restrict__ h_out, float* __restrict__ ws)
{
    __shared__ __align__(16) unsigned short s_inpb[128 * 104]; // inp; later h (stride 88)
    __shared__ __align__(16) unsigned short s_hinb[128 * 88];
    __shared__ __align__(16) unsigned short s_xb[128 * 88];
    __shared__ float s_stat[448];

    const int t = threadIdx.x;
    const int row0 = blockIdx.x * 128;
    const int lane = t & 63;
    const int w = t >> 6;
    const int n16 = lane & 15;
    const int quad = lane >> 4;

    {
        const float* gi = inp + (size_t)row0 * 96;
        for (int i = t; i < 3072; i += 256) {
            int r = i / 24, c4 = (i - r * 24) * 4;
            float4 v = *(const float4*)&gi[r * 96 + c4];
            u16x4 p; p.x = f2bf(v.x); p.y = f2bf(v.y); p.z = f2bf(v.z); p.w = f2bf(v.w);
            *(u16x4*)&s_inpb[r * 104 + c4] = p;
        }
        const float* gh = hin + (size_t)row0 * 64;
        for (int i = t; i < 2048; i += 256) {
            int r = i >> 4, c4 = (i & 15) * 4;
            float4 v = *(const float4*)&gh[r * 64 + c4];
            u16x4 p; p.x = f2bf(v.x); p.y = f2bf(v.y); p.z = f2bf(v.z); p.w = f2bf(v.w);
            *(u16x4*)&s_hinb[r * 88 + c4] = p;
        }
    }
    for (int i = t; i < 448; i += 256) s_stat[i] = 0.f;
    __syncthreads();

    const bhalf8* wp1 = (const bhalf8*)((const unsigned short*)(ws + WPACK_OFF));
    const bhalf8* wp2 = wp1 + 768;
    const bhalf8* wp3 = wp1 + 3840;

    // ---- P1: x = relu(inp @ fc1_w + b), both tiles ----
    {
        bhalf8 ai[2][3];
        #pragma unroll
        for (int u = 0; u < 2; u++) {
            int mr = w * 32 + u * 16 + n16;
            ai[u][0] = *(const bhalf8*)&s_inpb[mr * 104 + 0  + quad * 8];
            ai[u][1] = *(const bhalf8*)&s_inpb[mr * 104 + 32 + quad * 8];
            ai[u][2] = *(const bhalf8*)&s_inpb[mr * 104 + 64 + quad * 8];
        }
        #pragma unroll
        for (int g = 0; g < 4; g++) {
            bhalf8 f0 = wp1[(g * 3 + 0) * 64 + lane];
            bhalf8 f1 = wp1[(g * 3 + 1) * 64 + lane];
            bhalf8 f2 = wp1[(g * 3 + 2) * 64 + lane];
            int col = g * 16 + n16;
            float bb = fc1_b[col];
            #pragma unroll
            for (int u = 0; u < 2; u++) {
                floatx4 d = {0.f, 0.f, 0.f, 0.f};
                d = __builtin_amdgcn_mfma_f32_16x16x32_bf16(ai[u][0], f0, d, 0, 0, 0);
                d = __builtin_amdgcn_mfma_f32_16x16x32_bf16(ai[u][1], f1, d, 0, 0, 0);
                d = __builtin_amdgcn_mfma_f32_16x16x32_bf16(ai[u][2], f2, d, 0, 0, 0);
                #pragma unroll
                for (int q = 0; q < 4; q++) {
                    float xv = fmaxf(d[q] + bb, 0.f);
                    s_xb[(w * 32 + u * 16 + quad * 4 + q) * 88 + col] = f2bf(xv);
                }
            }
        }
    }
    // own-wave rows only -> no barrier before P2 A-frag reads

    // ---- P2 MFMA: 4 gate accumulators x 2 tiles; each frag feeds 2 MFMAs ----
    floatx4 gr[2][4], gz[2][4], gn[2][4], gh2[2][4];
    {
        bhalf8 ax0[2], ax1[2], ah0[2], ah1[2];
        #pragma unroll
        for (int u = 0; u < 2; u++) {
            int mr = w * 32 + u * 16 + n16;
            ax0[u] = *(const bhalf8*)&s_xb[mr * 88 + 0  + quad * 8];
            ax1[u] = *(const bhalf8*)&s_xb[mr * 88 + 32 + quad * 8];
            ah0[u] = *(const bhalf8*)&s_hinb[mr * 88 + 0  + quad * 8];
            ah1[u] = *(const bhalf8*)&s_hinb[mr * 88 + 32 + quad * 8];
        }
        #pragma unroll
        for (int g = 0; g < 4; g++) {
            {   // r gate
                bhalf8 f0 = wp2[((0 + g) * 2 + 0) * 64 + lane];
                bhalf8 f1 = wp2[((0 + g) * 2 + 1) * 64 + lane];
                bhalf8 f2 = wp2[((12 + g) * 2 + 0) * 64 + lane];
                bhalf8 f3 = wp2[((12 + g) * 2 + 1) * 64 + lane];
                #pragma unroll
                for (int u = 0; u < 2; u++) {
                    floatx4 d = {0.f, 0.f, 0.f, 0.f};
                    d = __builtin_amdgcn_mfma_f32_16x16x32_bf16(ax0[u], f0, d, 0, 0, 0);
                    d = __builtin_amdgcn_mfma_f32_16x16x32_bf16(ax1[u], f1, d, 0, 0, 0);
                    d = __builtin_amdgcn_mfma_f32_16x16x32_bf16(ah0[u], f2, d, 0, 0, 0);
                    d = __builtin_amdgcn_mfma_f32_16x16x32_bf16(ah1[u], f3, d, 0, 0, 0);
                    gr[u][g] = d;
                }
            }
            {   // z gate
                bhalf8 f0 = wp2[((4 + g) * 2 + 0) * 64 + lane];
                bhalf8 f1 = wp2[((4 + g) * 2 + 1) * 64 + lane];
                bhalf8 f2 = wp2[((16 + g) * 2 + 0) * 64 + lane];
                bhalf8 f3 = wp2[((16 + g) * 2 + 1) * 64 + lane];
                #pragma unroll
                for (int u = 0; u < 2; u++) {
                    floatx4 d = {0.f, 0.f, 0.f, 0.f};
                    d = __builtin_amdgcn_mfma_f32_16x16x32_bf16(ax0[u], f0, d, 0, 0, 0);
                    d = __builtin_amdgcn_mfma_f32_16x16x32_bf16(ax1[u], f1, d, 0, 0, 0);
                    d = __builtin_amdgcn_mfma_f32_16x16x32_bf16(ah0[u], f2, d, 0, 0, 0);
                    d = __builtin_amdgcn_mfma_f32_16x16x32_bf16(ah1[u], f3, d, 0, 0, 0);
                    gz[u][g] = d;
                }
            }
            {   // n (input half)
                bhalf8 f0 = wp2[((8 + g) * 2 + 0) * 64 + lane];
                bhalf8 f1 = wp2[((8 + g) * 2 + 1) * 64 + lane];
                #pragma unroll
                for (int u = 0; u < 2; u++) {
                    floatx4 d = {0.f, 0.f, 0.f, 0.f};
                    d = __builtin_amdgcn_mfma_f32_16x16x32_bf16(ax0[u], f0, d, 0, 0, 0);
                    d = __builtin_amdgcn_mfma_f32_16x16x32_bf16(ax1[u], f1, d, 0, 0, 0);
                    gn[u][g] = d;
                }
            }
            {   // n (hidden half)
                bhalf8 f0 = wp2[((20 + g) * 2 + 0) * 64 + lane];
                bhalf8 f1 = wp2[((20 + g) * 2 + 1) * 64 + lane];
                #pragma unroll
                for (int u = 0; u < 2; u++) {
                    floatx4 d = {0.f, 0.f, 0.f, 0.f};
                    d = __builtin_amdgcn_mfma_f32_16x16x32_bf16(ah0[u], f0, d, 0, 0, 0);
                    d = __builtin_amdgcn_mfma_f32_16x16x32_bf16(ah1[u], f1, d, 0, 0, 0);
                    gh2[u][g] = d;
                }
            }
        }
    }
    __syncthreads();   // P1/P2 LDS reads done before s_hb overlays s_inpb

    // ---- P2 post: gates -> h ----
    unsigned short* s_hb = s_inpb;   // stride 88
    #pragma unroll
    for (int g = 0; g < 4; g++) {
        int col = g * 16 + n16;
        float br_ = b_ih[col] + b_hh[col];
        float bz_ = b_ih[64 + col] + b_hh[64 + col];
        float bin_ = b_ih[128 + col];
        float bhn_ = b_hh[128 + col];
        #pragma unroll
        for (int u = 0; u < 2; u++) {
            #pragma unroll
            for (int q = 0; q < 4; q++) {
                int lrow = w * 32 + u * 16 + quad * 4 + q;
                size_t grow = (size_t)(row0 + lrow);
                float r  = sigmf(gr[u][g][q] + br_);
                float z  = sigmf(gz[u][g][q] + bz_);
                float nt = tanhfast(gn[u][g][q] + bin_ + r * (gh2[u][g][q] + bhn_));
                float hp = hin[grow * 64 + col];
                float h  = (1.f - z) * nt + z * hp;
                h_out[grow * 64 + col] = h;
                s_hb[lrow * 88 + col] = f2bf(h);
            }
        }
    }
    // own-wave rows only -> no barrier before P3 A-frag reads

    // ---- P3 MFMA: a1/U/V (stats only) ----
    {
        bhalf8 bh0[2], bh1[2];
        #pragma unroll
        for (int u = 0; u < 2; u++) {
            int mr = w * 32 + u * 16 + n16;
            bh0[u] = *(const bhalf8*)&s_hb[mr * 88 + 0  + quad * 8];
            bh1[u] = *(const bhalf8*)&s_hb[mr * 88 + 32 + quad * 8];
        }
        floatx4 g3[2][12];
        #pragma unroll
        for (int tt = 0; tt < 12; tt++) {
            bhalf8 f0 = wp3[(tt * 2 + 0) * 64 + lane];
            bhalf8 f1 = wp3[(tt * 2 + 1) * 64 + lane];
            #pragma unroll
            for (int u = 0; u < 2; u++) {
                floatx4 d = {0.f, 0.f, 0.f, 0.f};
                d = __builtin_amdgcn_mfma_f32_16x16x32_bf16(bh0[u], f0, d, 0, 0, 0);
                d = __builtin_amdgcn_mfma_f32_16x16x32_bf16(bh1[u], f1, d, 0, 0, 0);
                g3[u][tt] = d;
            }
        }
        #pragma unroll
        for (int g = 0; g < 4; g++) {
            int col = g * 16 + n16;
            float ab = aw1_b[col];
            float s1 = 0.f, s2 = 0.f, suq = 0.f, svq = 0.f;
            float su[2] = {0.f, 0.f}, sv[2] = {0.f, 0.f};
            #pragma unroll
            for (int u = 0; u < 2; u++) {
                #pragma unroll
                for (int q = 0; q < 4; q++) {
                    float a = g3[u][g][q] + ab; s1 += a; s2 += a * a;
                    float uv = g3[u][4 + g][q]; su[u] += uv; suq += uv * uv;
                    float vv = g3[u][8 + g][q]; sv[u] += vv; svq += vv * vv;
                }
            }
            #pragma unroll
            for (int u = 0; u < 2; u++) {      // cross term per 8-row b-group
                float u8 = su[u] + __shfl_xor(su[u], 16, 64);
                float v8 = sv[u] + __shfl_xor(sv[u], 16, 64);
                if ((quad & 1) == 0)
                    atomicAdd(&s_stat[384 + col], u8 * v8 * (1.f / 64.f));
            }
            float sut = su[0] + su[1];
            float svt = sv[0] + sv[1];
            float t1 = s1 + __shfl_xor(s1, 16, 64);  t1 += __shfl_xor(t1, 32, 64);
            float t2 = s2 + __shfl_xor(s2, 16, 64);  t2 += __shfl_xor(t2, 32, 64);
            float t3 = sut + __shfl_xor(sut, 16, 64); t3 += __shfl_xor(t3, 32, 64);
            float t4 = suq + __shfl_xor(suq, 16, 64); t4 += __shfl_xor(t4, 32, 64);
            float t5 = svt + __shfl_xor(svt, 16, 64); t5 += __shfl_xor(t5, 32, 64);
            float t6 = svq + __shfl_xor(svq, 16, 64); t6 += __shfl_xor(t6, 32, 64);
            if (quad == 0) {
                atomicAdd(&s_stat[col], t1);
                atomicAdd(&s_stat[64 + col], t2);
                atomicAdd(&s_stat[128 + col], t3);
                atomicAdd(&s_stat[192 + col], t4);
                atomicAdd(&s_stat[256 + col], t5);
                atomicAdd(&s_stat[320 + col], t6);
            }
        }
    }
    __syncthreads();
    if (t < 64) {
        float* gs = ws + STAT_OFF;
        #pragma unroll
        for (int q = 0; q < 7; q++)
            atomicAdd(&gs[q * 64 + t], s_stat[q * 64 + t]);
    }
}

// ---------------------------------------------------------------------------
// K2 (k_heads): fused stats-finalize + actor + critic head.  32 rows (4 b)
// per block, 128 thr.  Each block derives BN scale/shift + po2^T into LDS
// from the global stat accumulators (kernel-boundary visibility), recomputes
// a1/U/V from h via MFMA, pre-folds psc/psh into U'/V' (fp32 LDS), then
// actor (aw2->mu/sigma/c->fc2->x_out) and critic (pairwise relu -> po2 -> KL).
// LDS ~38.2 KB -> 4 blocks/CU.
// ---------------------------------------------------------------------------
__global__ __launch_bounds__(128) void k_heads(
    const float* __restrict__ h_glob, const float* __restrict__ noise,
    const float* __restrict__ aw1_b, const float* __restrict__ aw2_b,
    const float* __restrict__ fc2_b, const float* __restrict__ po2_b,
    const float* __restrict__ aw_g, const float* __restrict__ aw_be,
    const float* __restrict__ po_g, const float* __restrict__ po_be,
    const float* __restrict__ po1_b, const float* __restrict__ po2_w,
    const float* __restrict__ ws, float* __restrict__ out)
{
    __shared__ __align__(16) unsigned short s_hb[32 * 104]; // h | c | zero-pad
    __shared__ __align__(16) float s_Uf[32 * 68];           // psc*U
    __shared__ __align__(16) float s_Vf[32 * 68];           // psc*V + psh
    __shared__ float s_ms[32 * 48];                         // mu | sigma
    __shared__ __align__(16) float s_u2[32 * 48];           // s_ab (bf16) then s_out
    __shared__ __align__(16) float s_dv[640];               // asc ash psc psh | po2^T
    __shared__ float s_kl[32];

    const int t = threadIdx.x;
    const int row0 = blockIdx.x * 32;
    const int b0 = blockIdx.x * 4;
    const int lane = t & 63;
    const int w = t >> 6;
    const int n16 = lane & 15;
    const int quad = lane >> 4;
    const int mrow = w * 16 + n16;

    // ---- derive BN scale/shift from global stats (k_stats folded in) ----
    if (t < 64) {
        const float* st = ws + STAT_OFF;
        const float invN = 1.f / 65536.f;
        float am = st[t] * invN;
        float av = st[64 + t] * invN - am * am;
        float asc = aw_g[t] * rsqrtf(av + 1e-5f);
        s_dv[t] = asc;
        s_dv[64 + t] = aw_be[t] - asc * am;
        float Eu = st[128 + t] * invN;
        float vu = st[192 + t] * invN - Eu * Eu;
        float Ev = st[256 + t] * invN;
        float vv = st[320 + t] * invN - Ev * Ev;
        float cov = st[384 + t] * (1.f / 8192.f) - Eu * Ev;
        float my = Eu + Ev + po1_b[t];
        float vy = vu + vv + 2.f * cov;
        float psc = po_g[t] * rsqrtf(vy + 1e-5f);
        s_dv[128 + t] = psc;
        s_dv[192 + t] = po_be[t] + psc * (po1_b[t] - my);
    }
    for (int i = t; i < 384; i += 128) {
        int d = i >> 6, c = i & 63;
        s_dv[256 + i] = po2_w[c * 6 + d];     // po2^T [6][64]
    }

    // ---- stage h -> bf16 (cols 0-63); zero pad cols 88-95 ----
    {
        const float* gh = h_glob + (size_t)row0 * 64;
        for (int i = t; i < 512; i += 128) {
            int r = i >> 4, c4 = (i & 15) * 4;
            float4 v = *(const float4*)&gh[r * 64 + c4];
            u16x4 p; p.x = f2bf(v.x); p.y = f2bf(v.y); p.z = f2bf(v.z); p.w = f2bf(v.w);
            *(u16x4*)&s_hb[r * 104 + c4] = p;
        }
        for (int i = t; i < 64; i += 128) {
            int r = i >> 1, c4 = 88 + (i & 1) * 4;
            u16x4 z; z.x = 0; z.y = 0; z.z = 0; z.w = 0;
            *(u16x4*)&s_hb[r * 104 + c4] = z;
        }
    }
    __syncthreads();

    const bhalf8* wp3  = ((const bhalf8*)((const unsigned short*)(ws + WPACK_OFF))) + 3840;
    const bhalf8* wpa2 = wp3 + 1536;
    const bhalf8* wpf2 = wpa2 + 384;
    unsigned short* s_ab = (unsigned short*)s_u2;    // stride 72

    // ---- phase A: a1/U'/V' via MFMA ----
    {
        bhalf8 ah0 = *(const bhalf8*)&s_hb[mrow * 104 + 0  + quad * 8];
        bhalf8 ah1 = *(const bhalf8*)&s_hb[mrow * 104 + 32 + quad * 8];
        floatx4 g3[12];
        #pragma unroll
        for (int tt = 0; tt < 12; tt++) {
            floatx4 d = {0.f, 0.f, 0.f, 0.f};
            d = __builtin_amdgcn_mfma_f32_16x16x32_bf16(ah0, wp3[(tt * 2 + 0) * 64 + lane], d, 0, 0, 0);
            d = __builtin_amdgcn_mfma_f32_16x16x32_bf16(ah1, wp3[(tt * 2 + 1) * 64 + lane], d, 0, 0, 0);
            g3[tt] = d;
        }
        #pragma unroll
        for (int g = 0; g < 4; g++) {
            int col = g * 16 + n16;
            float ab = aw1_b[col];
            float asc = s_dv[col], ash = s_dv[64 + col];
            float psc = s_dv[128 + col], psh = s_dv[192 + col];
            #pragma unroll
            for (int q = 0; q < 4; q++) {
                int lrow = w * 16 + quad * 4 + q;
                float a = fmaxf(asc * (g3[g][q] + ab) + ash, 0.f);
                s_ab[lrow * 72 + col] = f2bf(a);
                s_Uf[lrow * 68 + col] = psc * g3[4 + g][q];
                s_Vf[lrow * 68 + col] = psc * g3[8 + g][q] + psh;
            }
        }
    }
    __syncthreads();

    // ---- phase B1: aw = a @ aw2_w + b -> mu / sigma ----
    {
        bhalf8 aa0 = *(const bhalf8*)&s_ab[mrow * 72 + 0  + quad * 8];
        bhalf8 aa1 = *(const bhalf8*)&s_ab[mrow * 72 + 32 + quad * 8];
        #pragma unroll
        for (int g = 0; g < 3; g++) {
            floatx4 d = {0.f, 0.f, 0.f, 0.f};
            d = __builtin_amdgcn_mfma_f32_16x16x32_bf16(aa0, wpa2[(g * 2 + 0) * 64 + lane], d, 0, 0, 0);
            d = __builtin_amdgcn_mfma_f32_16x16x32_bf16(aa1, wpa2[(g * 2 + 1) * 64 + lane], d, 0, 0, 0);
            int col = g * 16 + n16;
            float bb = aw2_b[col];
            #pragma unroll
            for (int q = 0; q < 4; q++) {
                int lrow = w * 16 + quad * 4 + q;
                float v = d[q] + bb;
                s_ms[lrow * 48 + col] = (col < 24) ? v : fmaxf(__expf(v), 0.2f);
            }
        }
    }
    __syncthreads();

    // ---- phase B2: c = mu + sqrt(sigma)*noise -> s_hb cols 64-87 (bf16) ----
    for (int i = t; i < 768; i += 128) {
        int r = i / 24, m = i - r * 24;
        float c = s_ms[r * 48 + m] + sqrtf(s_ms[r * 48 + 24 + m]) * noise[(size_t)(row0 + r) * 24 + m];
        s_hb[r * 104 + 64 + m] = f2bf(c);
    }
    __syncthreads();

    // ---- phase B3: x_out = [h,c] @ fc2_w + b ----
    {
        bhalf8 hc0 = *(const bhalf8*)&s_hb[mrow * 104 + 0  + quad * 8];
        bhalf8 hc1 = *(const bhalf8*)&s_hb[mrow * 104 + 32 + quad * 8];
        bhalf8 hc2 = *(const bhalf8*)&s_hb[mrow * 104 + 64 + quad * 8];
        floatx4 d = {0.f, 0.f, 0.f, 0.f};
        d = __builtin_amdgcn_mfma_f32_16x16x32_bf16(hc0, wpf2[0 * 64 + lane], d, 0, 0, 0);
        d = __builtin_amdgcn_mfma_f32_16x16x32_bf16(hc1, wpf2[1 * 64 + lane], d, 0, 0, 0);
        d = __builtin_amdgcn_mfma_f32_16x16x32_bf16(hc2, wpf2[2 * 64 + lane], d, 0, 0, 0);
        if (n16 < 14) {
            float bb = fc2_b[n16];
            float* xout = out + OUT_XOUT;
            #pragma unroll
            for (int q = 0; q < 4; q++) {
                size_t grow = (size_t)(row0 + w * 16 + quad * 4 + q);
                xout[grow * 14 + n16] = d[q] + bb;
            }
        }
    }
    __syncthreads();   // s_ab dead -> s_out overlay safe

    // ---- phase C: critic pairwise + po2 ----
    float* s_out = s_u2;               // stride 48
    {
        const float* p2t = s_dv + 256;   // [6][64]
        const int bl = t >> 5;         // local b (0..3)
        const int rem = t & 31;
        const int i_ = rem >> 2;       // i (0..7)
        const int j0 = (rem & 3) * 2;  // j base
        float acc[2][6];
        #pragma unroll
        for (int jj = 0; jj < 2; jj++)
            #pragma unroll
            for (int d = 0; d < 6; d++) acc[jj][d] = 0.f;

        for (int c = 0; c < 64; c += 4) {
            float vv[4]; *(float4*)vv = *(const float4*)&s_Vf[(bl * 8 + i_) * 68 + c];
            float wv[6][4];
            #pragma unroll
            for (int d = 0; d < 6; d++) *(float4*)wv[d] = *(const float4*)&p2t[d * 64 + c];
            #pragma unroll
            for (int jj = 0; jj < 2; jj++) {
                float uu[4]; *(float4*)uu = *(const float4*)&s_Uf[(bl * 8 + j0 + jj) * 68 + c];
                float p[4];
                #pragma unroll
                for (int q = 0; q < 4; q++) p[q] = fmaxf(uu[q] + vv[q], 0.f);
                #pragma unroll
                for (int d = 0; d < 6; d++)
                    acc[jj][d] += p[0] * wv[d][0] + p[1] * wv[d][1] + p[2] * wv[d][2] + p[3] * wv[d][3];
            }
        }
        #pragma unroll
        for (int jj = 0; jj < 2; jj++)
            #pragma unroll
            for (int d = 0; d < 6; d++)
                s_out[(bl * 8 + i_) * 48 + (j0 + jj) * 6 + d] = acc[jj][d] + po2_b[d];
    }
    __syncthreads();

    // ---- KL ----
    if (t < 32) {
        float s = 0.f;
        #pragma unroll 4
        for (int m = 0; m < 24; m++) {
            float mu0 = s_ms[t * 48 + m];
            float sg0 = s_ms[t * 48 + 24 + m];
            float mu1 = s_out[t * 48 + m];
            float sg1 = fmaxf(__expf(s_out[t * 48 + 24 + m]), 0.2f);
            float d0 = mu0 - mu1;
            s += __logf(sg1 / sg0) + (sg0 + d0 * d0) / sg1 - 1.f;
        }
        s_kl[t] = s;
    }
    __syncthreads();
    if (t < 4) {
        float s = 0.f;
        #pragma unroll
        for (int i = 0; i < 8; i++) s += s_kl[t * 8 + i];
        out[OUT_KL + b0 + t] = s * (0.5f / 192.f);
    }
}

// ---------------------------------------------------------------------------
extern "C" void kernel_launch(void* const* d_in, const int* in_sizes, int n_in,
                              void* d_out, int out_size, void* d_ws, size_t ws_size,
                              hipStream_t stream)
{
    (void)in_sizes; (void)n_in; (void)out_size; (void)ws_size;
    const float* inp   = (const float*)d_in[0];
    const float* hin   = (const float*)d_in[1];
    const float* noise = (const float*)d_in[2];
    const float* fc1_w = (const float*)d_in[3];
    const float* fc1_b = (const float*)d_in[4];
    const float* w_ih  = (const float*)d_in[5];
    const float* w_hh  = (const float*)d_in[6];
    const float* b_ih  = (const float*)d_in[7];
    const float* b_hh  = (const float*)d_in[8];
    const float* aw1_w = (const float*)d_in[9];
    const float* aw1_b = (const float*)d_in[10];
    const float* aw_g  = (const float*)d_in[11];
    const float* aw_be = (const float*)d_in[12];
    const float* aw2_w = (const float*)d_in[13];
    const float* aw2_b = (const float*)d_in[14];
    const float* po1_w = (const float*)d_in[15];
    const float* po1_b = (const float*)d_in[16];
    const float* po_g  = (const float*)d_in[17];
    const float* po_be = (const float*)d_in[18];
    const float* po2_w = (const float*)d_in[19];
    const float* po2_b = (const float*)d_in[20];
    const float* fc2_w = (const float*)d_in[21];
    const float* fc2_b = (const float*)d_in[22];
    float* out = (float*)d_out;
    float* ws  = (float*)d_ws;

    hipLaunchKernelGGL(k_prep,  dim3(24),   dim3(256), 0, stream,
                       fc1_w, w_ih, w_hh, aw1_w, po1_w, aw2_w, fc2_w, ws);
    hipLaunchKernelGGL(k_front, dim3(512),  dim3(256), 0, stream,
                       inp, hin, fc1_b, b_ih, b_hh, aw1_b, out + OUT_H, ws);
    hipLaunchKernelGGL(k_heads, dim3(2048), dim3(128), 0, stream,
                       out + OUT_H, noise, aw1_b, aw2_b, fc2_b, po2_b,
                       aw_g, aw_be, po_g, po_be, po1_b, po2_w, ws, out);
}

// Round 7
// 197.224 us; speedup vs baseline: 1.9452x; 1.0024x over previous
//
#include <hip/hip_runtime.h>
#include <math.h>

// ---------------------------------------------------------------------------
// Problem constants
// ---------------------------------------------------------------------------
#define NROWS 65536          // B*NAG = 8192*8
#define NB    8192           // B
// workspace layout (float offsets)
#define STAT_OFF  0          // 448 floats: asum asq usum usq vsum vsq cross
#define WPACK_OFF 448        // 5952 frags x 8 ushort = 47616 ushorts
// d_out layout (float offsets): x_out, h, KL
#define OUT_XOUT 0
#define OUT_H    917504
#define OUT_KL   5111808

typedef __attribute__((ext_vector_type(8))) short bhalf8;
typedef __attribute__((ext_vector_type(4))) float floatx4;
typedef __attribute__((ext_vector_type(4))) unsigned short u16x4;

__device__ __forceinline__ float sigmf(float x) { return 1.0f / (1.0f + __expf(-x)); }
__device__ __forceinline__ float tanhfast(float x) {
    x = fminf(fmaxf(x, -15.f), 15.f);
    float e = __expf(-2.f * x);
    return (1.f - e) / (1.f + e);
}
__device__ __forceinline__ unsigned short f2bf(float f) {   // RNE fp32->bf16
    unsigned int u = __float_as_uint(f);
    u += 0x7FFFu + ((u >> 16) & 1u);
    return (unsigned short)(u >> 16);
}
__device__ __forceinline__ float bf2f(unsigned short s) {
    return __uint_as_float(((unsigned int)s) << 16);
}
__device__ __forceinline__ bhalf8 pack8(float4 a, float4 b) {
    bhalf8 r;
    r[0] = (short)f2bf(a.x); r[1] = (short)f2bf(a.y);
    r[2] = (short)f2bf(a.z); r[3] = (short)f2bf(a.w);
    r[4] = (short)f2bf(b.x); r[5] = (short)f2bf(b.y);
    r[6] = (short)f2bf(b.z); r[7] = (short)f2bf(b.w);
    return r;
}

// ---------------------------------------------------------------------------
// K0 (k_prep): zero stat accumulators + pack ALL weights into bf16 MFMA
// B-fragment order.  Fragment = 16 cols x 32 k; lane (n=lane&15, quad=lane>>4)
// holds 8 contiguous bf16 for k = quad*8+j.   24 blocks -> single pass.
// ---------------------------------------------------------------------------
__global__ void k_prep(const float* __restrict__ fc1_w,
                       const float* __restrict__ w_ih, const float* __restrict__ w_hh,
                       const float* __restrict__ aw1_w, const float* __restrict__ po1_w,
                       const float* __restrict__ aw2_w, const float* __restrict__ fc2_w,
                       float* __restrict__ ws)
{
    const int t = threadIdx.x;
    if (blockIdx.x == 0)
        for (int i = t; i < 448; i += 256) ws[STAT_OFF + i] = 0.f;

    unsigned short* wpk = (unsigned short*)(ws + WPACK_OFF);
    for (int f = blockIdx.x * 256 + t; f < 5952; f += gridDim.x * 256) {
        int lane, c, tile;
        const float* src;
        int colbase, krowstride, kofs = 0, kmax = 1 << 30, colmax = 16;
        if (f < 768) {            // wp1
            tile = f / 192; c = (f % 192) / 64; lane = f % 64;
            src = fc1_w; krowstride = 64; colbase = tile * 16;
        } else if (f < 3840) {    // wp2
            int f2 = f - 768;
            tile = f2 / 128; c = (f2 % 128) / 64; lane = f2 % 64;
            if (tile < 12) { src = w_ih; colbase = tile * 16; }
            else           { src = w_hh; colbase = (tile - 12) * 16; }
            krowstride = 192;
        } else if (f < 5376) {    // wp3
            int f3 = f - 3840;
            tile = f3 / 128; c = (f3 % 128) / 64; lane = f3 % 64;
            if (tile < 4)       { src = aw1_w; colbase = tile * 16; }
            else if (tile < 8)  { src = po1_w; colbase = (tile - 4) * 16; }
            else                { src = po1_w; colbase = (tile - 8) * 16; kofs = 64; }
            krowstride = 64;
        } else if (f < 5760) {    // wpa2
            int f4 = f - 5376;
            tile = f4 / 128; c = (f4 % 128) / 64; lane = f4 % 64;
            src = aw2_w; krowstride = 48; colbase = tile * 16;
        } else {                  // wpf2
            int f5 = f - 5760;
            c = f5 / 64; lane = f5 % 64;
            src = fc2_w; krowstride = 14; colbase = 0;
            kmax = 88; colmax = 14;
        }
        int n = lane & 15, quad = lane >> 4;
        int col = colbase + n;
        unsigned short o[8];
        #pragma unroll
        for (int j = 0; j < 8; j++) {
            int k = c * 32 + quad * 8 + j + kofs;
            float v = (k < kmax && n < colmax) ? src[(size_t)k * krowstride + col] : 0.f;
            o[j] = f2bf(v);
        }
        u16x4 lo, hi;
        lo.x = o[0]; lo.y = o[1]; lo.z = o[2]; lo.w = o[3];
        hi.x = o[4]; hi.y = o[5]; hi.z = o[6]; hi.w = o[7];
        *(u16x4*)&wpk[f * 8]     = lo;
        *(u16x4*)&wpk[f * 8 + 4] = hi;
    }
}

// ---------------------------------------------------------------------------
// K1: fc1 -> GRU -> h + BN stat partials.  128 rows/block, 256 thr (4 waves,
// 2 m-tiles/wave).  A-fragments of inp/h_in loaded DIRECTLY from global (no
// LDS staging, no duplication, no barrier); only x/h round-trips through a
// wave-private LDS buffer (stride 80 -> aligned b128).  P2/P3 are per-g so
// only 8 accumulators are live.  LDS 22.3 KB, 2 barriers total.
// ---------------------------------------------------------------------------
__global__ __launch_bounds__(256, 4) void k_front(
    const float* __restrict__ inp, const float* __restrict__ hin,
    const float* __restrict__ fc1_b,
    const float* __restrict__ b_ih, const float* __restrict__ b_hh,
    const float* __restrict__ aw1_b,
    float* __restrict__ h_out, float* __restrict__ ws)
{
    __shared__ __align__(16) unsigned short s_xb[128 * 80];  // x, then h (wave-private rows)
    __shared__ float s_stat[448];

    const int t = threadIdx.x;
    const int row0 = blockIdx.x * 128;
    const int lane = t & 63;
    const int w = t >> 6;
    const int n16 = lane & 15;
    const int quad = lane >> 4;

    for (int i = t; i < 448; i += 256) s_stat[i] = 0.f;
    __syncthreads();

    const bhalf8* wp1 = (const bhalf8*)((const unsigned short*)(ws + WPACK_OFF));
    const bhalf8* wp2 = wp1 + 768;
    const bhalf8* wp3 = wp1 + 3840;

    // ---- A-frag direct global loads: inp (3 kchunks), h_in (2 kchunks) ----
    bhalf8 ai[2][3], ahf[2][2];
    #pragma unroll
    for (int u = 0; u < 2; u++) {
        const float* gi = inp + (size_t)(row0 + w * 32 + u * 16 + n16) * 96 + quad * 8;
        #pragma unroll
        for (int kc = 0; kc < 3; kc++)
            ai[u][kc] = pack8(*(const float4*)&gi[kc * 32], *(const float4*)&gi[kc * 32 + 4]);
        const float* gh = hin + (size_t)(row0 + w * 32 + u * 16 + n16) * 64 + quad * 8;
        #pragma unroll
        for (int kc = 0; kc < 2; kc++)
            ahf[u][kc] = pack8(*(const float4*)&gh[kc * 32], *(const float4*)&gh[kc * 32 + 4]);
    }

    // ---- P1: x = relu(inp @ fc1_w + b) ----
    #pragma unroll
    for (int g = 0; g < 4; g++) {
        bhalf8 f0 = wp1[(g * 3 + 0) * 64 + lane];
        bhalf8 f1 = wp1[(g * 3 + 1) * 64 + lane];
        bhalf8 f2 = wp1[(g * 3 + 2) * 64 + lane];
        int col = g * 16 + n16;
        float bb = fc1_b[col];
        #pragma unroll
        for (int u = 0; u < 2; u++) {
            floatx4 d = {0.f, 0.f, 0.f, 0.f};
            d = __builtin_amdgcn_mfma_f32_16x16x32_bf16(ai[u][0], f0, d, 0, 0, 0);
            d = __builtin_amdgcn_mfma_f32_16x16x32_bf16(ai[u][1], f1, d, 0, 0, 0);
            d = __builtin_amdgcn_mfma_f32_16x16x32_bf16(ai[u][2], f2, d, 0, 0, 0);
            #pragma unroll
            for (int q = 0; q < 4; q++)
                s_xb[(w * 32 + u * 16 + quad * 4 + q) * 80 + col] = f2bf(fmaxf(d[q] + bb, 0.f));
        }
    }
    // x A-frags (own-wave rows; same-wave DS ordering makes this safe)
    bhalf8 ax[2][2];
    #pragma unroll
    for (int u = 0; u < 2; u++) {
        int mr = w * 32 + u * 16 + n16;
        ax[u][0] = *(const bhalf8*)&s_xb[mr * 80 + 0  + quad * 8];
        ax[u][1] = *(const bhalf8*)&s_xb[mr * 80 + 32 + quad * 8];
    }

    // ---- P2 per-g: gates -> h (8 accs live; h overlays x in s_xb) ----
    #pragma unroll
    for (int g = 0; g < 4; g++) {
        int col = g * 16 + n16;
        floatx4 dr[2], dz[2], dn[2], dh[2];
        {
            bhalf8 f0 = wp2[((0 + g) * 2 + 0) * 64 + lane];
            bhalf8 f1 = wp2[((0 + g) * 2 + 1) * 64 + lane];
            bhalf8 f2 = wp2[((12 + g) * 2 + 0) * 64 + lane];
            bhalf8 f3 = wp2[((12 + g) * 2 + 1) * 64 + lane];
            #pragma unroll
            for (int u = 0; u < 2; u++) {
                floatx4 d = {0.f, 0.f, 0.f, 0.f};
                d = __builtin_amdgcn_mfma_f32_16x16x32_bf16(ax[u][0], f0, d, 0, 0, 0);
                d = __builtin_amdgcn_mfma_f32_16x16x32_bf16(ax[u][1], f1, d, 0, 0, 0);
                d = __builtin_amdgcn_mfma_f32_16x16x32_bf16(ahf[u][0], f2, d, 0, 0, 0);
                d = __builtin_amdgcn_mfma_f32_16x16x32_bf16(ahf[u][1], f3, d, 0, 0, 0);
                dr[u] = d;
            }
        }
        {
            bhalf8 f0 = wp2[((4 + g) * 2 + 0) * 64 + lane];
            bhalf8 f1 = wp2[((4 + g) * 2 + 1) * 64 + lane];
            bhalf8 f2 = wp2[((16 + g) * 2 + 0) * 64 + lane];
            bhalf8 f3 = wp2[((16 + g) * 2 + 1) * 64 + lane];
            #pragma unroll
            for (int u = 0; u < 2; u++) {
                floatx4 d = {0.f, 0.f, 0.f, 0.f};
                d = __builtin_amdgcn_mfma_f32_16x16x32_bf16(ax[u][0], f0, d, 0, 0, 0);
                d = __builtin_amdgcn_mfma_f32_16x16x32_bf16(ax[u][1], f1, d, 0, 0, 0);
                d = __builtin_amdgcn_mfma_f32_16x16x32_bf16(ahf[u][0], f2, d, 0, 0, 0);
                d = __builtin_amdgcn_mfma_f32_16x16x32_bf16(ahf[u][1], f3, d, 0, 0, 0);
                dz[u] = d;
            }
        }
        {
            bhalf8 f0 = wp2[((8 + g) * 2 + 0) * 64 + lane];
            bhalf8 f1 = wp2[((8 + g) * 2 + 1) * 64 + lane];
            #pragma unroll
            for (int u = 0; u < 2; u++) {
                floatx4 d = {0.f, 0.f, 0.f, 0.f};
                d = __builtin_amdgcn_mfma_f32_16x16x32_bf16(ax[u][0], f0, d, 0, 0, 0);
                d = __builtin_amdgcn_mfma_f32_16x16x32_bf16(ax[u][1], f1, d, 0, 0, 0);
                dn[u] = d;
            }
        }
        {
            bhalf8 f0 = wp2[((20 + g) * 2 + 0) * 64 + lane];
            bhalf8 f1 = wp2[((20 + g) * 2 + 1) * 64 + lane];
            #pragma unroll
            for (int u = 0; u < 2; u++) {
                floatx4 d = {0.f, 0.f, 0.f, 0.f};
                d = __builtin_amdgcn_mfma_f32_16x16x32_bf16(ahf[u][0], f0, d, 0, 0, 0);
                d = __builtin_amdgcn_mfma_f32_16x16x32_bf16(ahf[u][1], f1, d, 0, 0, 0);
                dh[u] = d;
            }
        }
        float br_ = b_ih[col] + b_hh[col];
        float bz_ = b_ih[64 + col] + b_hh[64 + col];
        float bin_ = b_ih[128 + col];
        float bhn_ = b_hh[128 + col];
        #pragma unroll
        for (int u = 0; u < 2; u++) {
            #pragma unroll
            for (int q = 0; q < 4; q++) {
                int lrow = w * 32 + u * 16 + quad * 4 + q;
                size_t grow = (size_t)(row0 + lrow);
                float r  = sigmf(dr[u][q] + br_);
                float z  = sigmf(dz[u][q] + bz_);
                float nt = tanhfast(dn[u][q] + bin_ + r * (dh[u][q] + bhn_));
                float hp = hin[grow * 64 + col];
                float h  = (1.f - z) * nt + z * hp;
                h_out[grow * 64 + col] = h;
                s_xb[lrow * 80 + col] = f2bf(h);   // overlay x (x lives in ax regs)
            }
        }
    }

    // h A-frags (own-wave rows)
    bhalf8 hh[2][2];
    #pragma unroll
    for (int u = 0; u < 2; u++) {
        int mr = w * 32 + u * 16 + n16;
        hh[u][0] = *(const bhalf8*)&s_xb[mr * 80 + 0  + quad * 8];
        hh[u][1] = *(const bhalf8*)&s_xb[mr * 80 + 32 + quad * 8];
    }

    // ---- P3 per-g: a1/U/V stats only ----
    #pragma unroll
    for (int g = 0; g < 4; g++) {
        int col = g * 16 + n16;
        floatx4 da[2], du[2], dvv[2];
        {
            bhalf8 f0 = wp3[(g * 2 + 0) * 64 + lane];
            bhalf8 f1 = wp3[(g * 2 + 1) * 64 + lane];
            #pragma unroll
            for (int u = 0; u < 2; u++) {
                floatx4 d = {0.f, 0.f, 0.f, 0.f};
                d = __builtin_amdgcn_mfma_f32_16x16x32_bf16(hh[u][0], f0, d, 0, 0, 0);
                d = __builtin_amdgcn_mfma_f32_16x16x32_bf16(hh[u][1], f1, d, 0, 0, 0);
                da[u] = d;
            }
        }
        {
            bhalf8 f0 = wp3[((4 + g) * 2 + 0) * 64 + lane];
            bhalf8 f1 = wp3[((4 + g) * 2 + 1) * 64 + lane];
            #pragma unroll
            for (int u = 0; u < 2; u++) {
                floatx4 d = {0.f, 0.f, 0.f, 0.f};
                d = __builtin_amdgcn_mfma_f32_16x16x32_bf16(hh[u][0], f0, d, 0, 0, 0);
                d = __builtin_amdgcn_mfma_f32_16x16x32_bf16(hh[u][1], f1, d, 0, 0, 0);
                du[u] = d;
            }
        }
        {
            bhalf8 f0 = wp3[((8 + g) * 2 + 0) * 64 + lane];
            bhalf8 f1 = wp3[((8 + g) * 2 + 1) * 64 + lane];
            #pragma unroll
            for (int u = 0; u < 2; u++) {
                floatx4 d = {0.f, 0.f, 0.f, 0.f};
                d = __builtin_amdgcn_mfma_f32_16x16x32_bf16(hh[u][0], f0, d, 0, 0, 0);
                d = __builtin_amdgcn_mfma_f32_16x16x32_bf16(hh[u][1], f1, d, 0, 0, 0);
                dvv[u] = d;
            }
        }
        float ab = aw1_b[col];
        float s1 = 0.f, s2 = 0.f, suq = 0.f, svq = 0.f;
        float su[2] = {0.f, 0.f}, sv[2] = {0.f, 0.f};
        #pragma unroll
        for (int u = 0; u < 2; u++) {
            #pragma unroll
            for (int q = 0; q < 4; q++) {
                float a = da[u][q] + ab; s1 += a; s2 += a * a;
                float uv = du[u][q]; su[u] += uv; suq += uv * uv;
                float vv = dvv[u][q]; sv[u] += vv; svq += vv * vv;
            }
        }
        #pragma unroll
        for (int u = 0; u < 2; u++) {      // cross term per 8-row b-group
            float u8 = su[u] + __shfl_xor(su[u], 16, 64);
            float v8 = sv[u] + __shfl_xor(sv[u], 16, 64);
            if ((quad & 1) == 0)
                atomicAdd(&s_stat[384 + col], u8 * v8 * (1.f / 64.f));
        }
        float sut = su[0] + su[1];
        float svt = sv[0] + sv[1];
        float t1 = s1 + __shfl_xor(s1, 16, 64);   t1 += __shfl_xor(t1, 32, 64);
        float t2 = s2 + __shfl_xor(s2, 16, 64);   t2 += __shfl_xor(t2, 32, 64);
        float t3 = sut + __shfl_xor(sut, 16, 64); t3 += __shfl_xor(t3, 32, 64);
        float t4 = suq + __shfl_xor(suq, 16, 64); t4 += __shfl_xor(t4, 32, 64);
        float t5 = svt + __shfl_xor(svt, 16, 64); t5 += __shfl_xor(t5, 32, 64);
        float t6 = svq + __shfl_xor(svq, 16, 64); t6 += __shfl_xor(t6, 32, 64);
        if (quad == 0) {
            atomicAdd(&s_stat[col], t1);
            atomicAdd(&s_stat[64 + col], t2);
            atomicAdd(&s_stat[128 + col], t3);
            atomicAdd(&s_stat[192 + col], t4);
            atomicAdd(&s_stat[256 + col], t5);
            atomicAdd(&s_stat[320 + col], t6);
        }
    }
    __syncthreads();
    if (t < 64) {
        float* gs = ws + STAT_OFF;
        #pragma unroll
        for (int q = 0; q < 7; q++)
            atomicAdd(&gs[q * 64 + t], s_stat[q * 64 + t]);
    }
}

// ---------------------------------------------------------------------------
// K2 (k_heads): fused stats-finalize + actor + critic head.  32 rows (4 b)
// per block, 128 thr.  BN scale/shift derived in-block; a1/U'/V' recomputed
// from h via MFMA; U'/V'/a stored bf16 at aligned stride 80; s_ab aliases
// s_out.  LDS ~32 KB -> 5 blocks/CU.
// ---------------------------------------------------------------------------
__global__ __launch_bounds__(128) void k_heads(
    const float* __restrict__ h_glob, const float* __restrict__ noise,
    const float* __restrict__ aw1_b, const float* __restrict__ aw2_b,
    const float* __restrict__ fc2_b, const float* __restrict__ po2_b,
    const float* __restrict__ aw_g, const float* __restrict__ aw_be,
    const float* __restrict__ po_g, const float* __restrict__ po_be,
    const float* __restrict__ po1_b, const float* __restrict__ po2_w,
    const float* __restrict__ ws, float* __restrict__ out)
{
    __shared__ __align__(16) unsigned short s_hb[32 * 104]; // h | c | zero-pad
    __shared__ __align__(16) unsigned short s_Ub[32 * 80];  // bf16 psc*U
    __shared__ __align__(16) unsigned short s_Vb[32 * 80];  // bf16 psc*V + psh
    __shared__ float s_ms[32 * 48];                         // mu | sigma
    __shared__ __align__(16) float s_out[32 * 48];          // s_ab (bf16, str 80) then out
    __shared__ __align__(16) float s_dv[640];               // asc ash psc psh | po2^T
    __shared__ float s_kl[32];

    const int t = threadIdx.x;
    const int row0 = blockIdx.x * 32;
    const int b0 = blockIdx.x * 4;
    const int lane = t & 63;
    const int w = t >> 6;
    const int n16 = lane & 15;
    const int quad = lane >> 4;
    const int mrow = w * 16 + n16;

    // ---- derive BN scale/shift from global stats ----
    if (t < 64) {
        const float* st = ws + STAT_OFF;
        const float invN = 1.f / 65536.f;
        float am = st[t] * invN;
        float av = st[64 + t] * invN - am * am;
        float asc = aw_g[t] * rsqrtf(av + 1e-5f);
        s_dv[t] = asc;
        s_dv[64 + t] = aw_be[t] - asc * am;
        float Eu = st[128 + t] * invN;
        float vu = st[192 + t] * invN - Eu * Eu;
        float Ev = st[256 + t] * invN;
        float vv = st[320 + t] * invN - Ev * Ev;
        float cov = st[384 + t] * (1.f / 8192.f) - Eu * Ev;
        float my = Eu + Ev + po1_b[t];
        float vy = vu + vv + 2.f * cov;
        float psc = po_g[t] * rsqrtf(vy + 1e-5f);
        s_dv[128 + t] = psc;
        s_dv[192 + t] = po_be[t] + psc * (po1_b[t] - my);
    }
    for (int i = t; i < 384; i += 128) {
        int d = i >> 6, c = i & 63;
        s_dv[256 + i] = po2_w[c * 6 + d];     // po2^T [6][64]
    }

    // ---- stage h -> bf16 (cols 0-63); zero pad cols 88-95 ----
    {
        const float* gh = h_glob + (size_t)row0 * 64;
        for (int i = t; i < 512; i += 128) {
            int r = i >> 4, c4 = (i & 15) * 4;
            float4 v = *(const float4*)&gh[r * 64 + c4];
            u16x4 p; p.x = f2bf(v.x); p.y = f2bf(v.y); p.z = f2bf(v.z); p.w = f2bf(v.w);
            *(u16x4*)&s_hb[r * 104 + c4] = p;
        }
        for (int i = t; i < 64; i += 128) {
            int r = i >> 1, c4 = 88 + (i & 1) * 4;
            u16x4 z; z.x = 0; z.y = 0; z.z = 0; z.w = 0;
            *(u16x4*)&s_hb[r * 104 + c4] = z;
        }
    }
    __syncthreads();

    const bhalf8* wp3  = ((const bhalf8*)((const unsigned short*)(ws + WPACK_OFF))) + 3840;
    const bhalf8* wpa2 = wp3 + 1536;
    const bhalf8* wpf2 = wpa2 + 384;
    unsigned short* s_ab = (unsigned short*)s_out;    // stride 80, dead before C

    // ---- phase A: a1/U'/V' via MFMA, per-g (low reg pressure) ----
    {
        bhalf8 ah0 = *(const bhalf8*)&s_hb[mrow * 104 + 0  + quad * 8];
        bhalf8 ah1 = *(const bhalf8*)&s_hb[mrow * 104 + 32 + quad * 8];
        #pragma unroll
        for (int g = 0; g < 4; g++) {
            int col = g * 16 + n16;
            floatx4 da = {0.f, 0.f, 0.f, 0.f}, duu = {0.f, 0.f, 0.f, 0.f}, dvv = {0.f, 0.f, 0.f, 0.f};
            da  = __builtin_amdgcn_mfma_f32_16x16x32_bf16(ah0, wp3[(g * 2 + 0) * 64 + lane], da, 0, 0, 0);
            da  = __builtin_amdgcn_mfma_f32_16x16x32_bf16(ah1, wp3[(g * 2 + 1) * 64 + lane], da, 0, 0, 0);
            duu = __builtin_amdgcn_mfma_f32_16x16x32_bf16(ah0, wp3[((4 + g) * 2 + 0) * 64 + lane], duu, 0, 0, 0);
            duu = __builtin_amdgcn_mfma_f32_16x16x32_bf16(ah1, wp3[((4 + g) * 2 + 1) * 64 + lane], duu, 0, 0, 0);
            dvv = __builtin_amdgcn_mfma_f32_16x16x32_bf16(ah0, wp3[((8 + g) * 2 + 0) * 64 + lane], dvv, 0, 0, 0);
            dvv = __builtin_amdgcn_mfma_f32_16x16x32_bf16(ah1, wp3[((8 + g) * 2 + 1) * 64 + lane], dvv, 0, 0, 0);
            float ab = aw1_b[col];
            float asc = s_dv[col], ash = s_dv[64 + col];
            float psc = s_dv[128 + col], psh = s_dv[192 + col];
            #pragma unroll
            for (int q = 0; q < 4; q++) {
                int lrow = w * 16 + quad * 4 + q;
                s_ab[lrow * 80 + col] = f2bf(fmaxf(asc * (da[q] + ab) + ash, 0.f));
                s_Ub[lrow * 80 + col] = f2bf(psc * duu[q]);
                s_Vb[lrow * 80 + col] = f2bf(psc * dvv[q] + psh);
            }
        }
    }
    // s_ab read below is own-wave rows -> no barrier

    // ---- phase B1: aw = a @ aw2_w + b -> mu / sigma ----
    {
        bhalf8 aa0 = *(const bhalf8*)&s_ab[mrow * 80 + 0  + quad * 8];
        bhalf8 aa1 = *(const bhalf8*)&s_ab[mrow * 80 + 32 + quad * 8];
        #pragma unroll
        for (int g = 0; g < 3; g++) {
            floatx4 d = {0.f, 0.f, 0.f, 0.f};
            d = __builtin_amdgcn_mfma_f32_16x16x32_bf16(aa0, wpa2[(g * 2 + 0) * 64 + lane], d, 0, 0, 0);
            d = __builtin_amdgcn_mfma_f32_16x16x32_bf16(aa1, wpa2[(g * 2 + 1) * 64 + lane], d, 0, 0, 0);
            int col = g * 16 + n16;
            float bb = aw2_b[col];
            #pragma unroll
            for (int q = 0; q < 4; q++) {
                int lrow = w * 16 + quad * 4 + q;
                float v = d[q] + bb;
                s_ms[lrow * 48 + col] = (col < 24) ? v : fmaxf(__expf(v), 0.2f);
            }
        }
    }
    __syncthreads();

    // ---- phase B2: c = mu + sqrt(sigma)*noise -> s_hb cols 64-87 (bf16) ----
    for (int i = t; i < 768; i += 128) {
        int r = i / 24, m = i - r * 24;
        float c = s_ms[r * 48 + m] + sqrtf(s_ms[r * 48 + 24 + m]) * noise[(size_t)(row0 + r) * 24 + m];
        s_hb[r * 104 + 64 + m] = f2bf(c);
    }
    __syncthreads();

    // ---- phase B3: x_out = [h,c] @ fc2_w + b ----
    {
        bhalf8 hc0 = *(const bhalf8*)&s_hb[mrow * 104 + 0  + quad * 8];
        bhalf8 hc1 = *(const bhalf8*)&s_hb[mrow * 104 + 32 + quad * 8];
        bhalf8 hc2 = *(const bhalf8*)&s_hb[mrow * 104 + 64 + quad * 8];
        floatx4 d = {0.f, 0.f, 0.f, 0.f};
        d = __builtin_amdgcn_mfma_f32_16x16x32_bf16(hc0, wpf2[0 * 64 + lane], d, 0, 0, 0);
        d = __builtin_amdgcn_mfma_f32_16x16x32_bf16(hc1, wpf2[1 * 64 + lane], d, 0, 0, 0);
        d = __builtin_amdgcn_mfma_f32_16x16x32_bf16(hc2, wpf2[2 * 64 + lane], d, 0, 0, 0);
        if (n16 < 14) {
            float bb = fc2_b[n16];
            float* xout = out + OUT_XOUT;
            #pragma unroll
            for (int q = 0; q < 4; q++) {
                size_t grow = (size_t)(row0 + w * 16 + quad * 4 + q);
                xout[grow * 14 + n16] = d[q] + bb;
            }
        }
    }
    __syncthreads();   // s_ab dead -> s_out overlay safe; s_Ub/s_Vb visible

    // ---- phase C: critic pairwise + po2 ----
    {
        const float* p2t = s_dv + 256;   // [6][64]
        const int bl = t >> 5;         // local b (0..3)
        const int rem = t & 31;
        const int i_ = rem >> 2;       // i (0..7)
        const int j0 = (rem & 3) * 2;  // j base
        float acc[2][6];
        #pragma unroll
        for (int jj = 0; jj < 2; jj++)
            #pragma unroll
            for (int d = 0; d < 6; d++) acc[jj][d] = 0.f;

        for (int c = 0; c < 64; c += 4) {
            u16x4 vb4 = *(const u16x4*)&s_Vb[(bl * 8 + i_) * 80 + c];
            float vv[4] = {bf2f(vb4.x), bf2f(vb4.y), bf2f(vb4.z), bf2f(vb4.w)};
            float wv[6][4];
            #pragma unroll
            for (int d = 0; d < 6; d++) *(float4*)wv[d] = *(const float4*)&p2t[d * 64 + c];
            #pragma unroll
            for (int jj = 0; jj < 2; jj++) {
                u16x4 ub4 = *(const u16x4*)&s_Ub[(bl * 8 + j0 + jj) * 80 + c];
                float p[4];
                p[0] = fmaxf(bf2f(ub4.x) + vv[0], 0.f);
                p[1] = fmaxf(bf2f(ub4.y) + vv[1], 0.f);
                p[2] = fmaxf(bf2f(ub4.z) + vv[2], 0.f);
                p[3] = fmaxf(bf2f(ub4.w) + vv[3], 0.f);
                #pragma unroll
                for (int d = 0; d < 6; d++)
                    acc[jj][d] += p[0] * wv[d][0] + p[1] * wv[d][1] + p[2] * wv[d][2] + p[3] * wv[d][3];
            }
        }
        #pragma unroll
        for (int jj = 0; jj < 2; jj++)
            #pragma unroll
            for (int d = 0; d < 6; d++)
                s_out[(bl * 8 + i_) * 48 + (j0 + jj) * 6 + d] = acc[jj][d] + po2_b[d];
    }
    __syncthreads();

    // ---- KL ----
    if (t < 32) {
        float s = 0.f;
        #pragma unroll 4
        for (int m = 0; m < 24; m++) {
            float mu0 = s_ms[t * 48 + m];
            float sg0 = s_ms[t * 48 + 24 + m];
            float mu1 = s_out[t * 48 + m];
            float sg1 = fmaxf(__expf(s_out[t * 48 + 24 + m]), 0.2f);
            float d0 = mu0 - mu1;
            s += __logf(sg1 / sg0) + (sg0 + d0 * d0) / sg1 - 1.f;
        }
        s_kl[t] = s;
    }
    __syncthreads();
    if (t < 4) {
        float s = 0.f;
        #pragma unroll
        for (int i = 0; i < 8; i++) s += s_kl[t * 8 + i];
        out[OUT_KL + b0 + t] = s * (0.5f / 192.f);
    }
}

// ---------------------------------------------------------------------------
extern "C" void kernel_launch(void* const* d_in, const int* in_sizes, int n_in,
                              void* d_out, int out_size, void* d_ws, size_t ws_size,
                              hipStream_t stream)
{
    (void)in_sizes; (void)n_in; (void)out_size; (void)ws_size;
    const float* inp   = (const float*)d_in[0];
    const float* hin   = (const float*)d_in[1];
    const float* noise = (const float*)d_in[2];
    const float* fc1_w = (const float*)d_in[3];
    const float* fc1_b = (const float*)d_in[4];
    const float* w_ih  = (const float*)d_in[5];
    const float* w_hh  = (const float*)d_in[6];
    const float* b_ih  = (const float*)d_in[7];
    const float* b_hh  = (const float*)d_in[8];
    const float* aw1_w = (const float*)d_in[9];
    const float* aw1_b = (const float*)d_in[10];
    const float* aw_g  = (const float*)d_in[11];
    const float* aw_be = (const float*)d_in[12];
    const float* aw2_w = (const float*)d_in[13];
    const float* aw2_b = (const float*)d_in[14];
    const float* po1_w = (const float*)d_in[15];
    const float* po1_b = (const float*)d_in[16];
    const float* po_g  = (const float*)d_in[17];
    const float* po_be = (const float*)d_in[18];
    const float* po2_w = (const float*)d_in[19];
    const float* po2_b = (const float*)d_in[20];
    const float* fc2_w = (const float*)d_in[21];
    const float* fc2_b = (const float*)d_in[22];
    float* out = (float*)d_out;
    float* ws  = (float*)d_ws;

    hipLaunchKernelGGL(k_prep,  dim3(24),   dim3(256), 0, stream,
                       fc1_w, w_ih, w_hh, aw1_w, po1_w, aw2_w, fc2_w, ws);
    hipLaunchKernelGGL(k_front, dim3(512),  dim3(256), 0, stream,
                       inp, hin, fc1_b, b_ih, b_hh, aw1_b, out + OUT_H, ws);
    hipLaunchKernelGGL(k_heads, dim3(2048), dim3(128), 0, stream,
                       out + OUT_H, noise, aw1_b, aw2_b, fc2_b, po2_b,
                       aw_g, aw_be, po_g, po_be, po1_b, po2_w, ws, out);
}